// Round 7
// baseline (949.917 us; speedup 1.0000x reference)
//
#include <hip/hip_runtime.h>
#include <hip/hip_bf16.h>

#define TT 6
#define NN 50000
#define EE 800000
#define FF 32
#define HH 64
#define OO 16

#define NB 256        // dst buckets
#define DPB 196       // dsts per bucket (256*196 = 50176 >= 50000)
#define CHUNK 4096    // edges per block in scatter
#define CAP 4096      // slab capacity per (t,bucket): mean 3125, sd 56 -> 17 sigma
#define SCAP 8192     // sorted-edge LDS capacity

// fused weight buffer layout (float offsets)
#define OFF_M 0        // M[g][32][64], g = z,r,h : W_g @ L_g[:64]
#define OFF_B 6144     // B[g][64][64]            : L_g[64:]
#define OFF_C 18432    // c[g][64]                : b_g @ L_g[:64] + L_g_b
#define OFF_OW 18624   // out_W [64][16]
#define OFF_OB 19648   // out_b [16]
#define WBUF_N 19664

typedef unsigned short ushort_t;

__device__ __forceinline__ float ldf(const void* p, int i){ return ((const float*)p)[i]; }
__device__ __forceinline__ float ubf(ushort_t v){ return __uint_as_float(((unsigned)v) << 16); }
__device__ __forceinline__ ushort_t f2b(float f){
  unsigned u = __float_as_uint(f);
  return (ushort_t)((u + 0x7FFFu + ((u >> 16) & 1u)) >> 16);
}

// ---------------- zero ----------------
__global__ void zero_kernel(uint4* __restrict__ p, int n4){
  int i = blockIdx.x*256 + threadIdx.x;
  if (i < n4) p[i] = make_uint4(0,0,0,0);
}

// ---------------- f32 -> bf16 convert (xs -> xb) ----------------
__global__ void cvt_kernel(const float4* __restrict__ x, ushort4* __restrict__ xb, int n4){
  int i = blockIdx.x*256 + threadIdx.x;
  if (i < n4){
    float4 v = x[i];
    ushort4 o;
    o.x = f2b(v.x); o.y = f2b(v.y); o.z = f2b(v.z); o.w = f2b(v.w);
    xb[i] = o;
  }
}

// ---------------- fused-weight prep (all inputs f32) ----------------
__global__ void prep_kernel(const void* Wz,const void* bz,const void* Wr,const void* br,
                            const void* Wh,const void* bh,
                            const void* Lz,const void* Lzb,const void* Lr,const void* Lrb,
                            const void* Lh,const void* Lhb,
                            const void* oW,const void* ob, float* __restrict__ wbuf){
  int idx = blockIdx.x*256 + threadIdx.x;
  if (idx >= WBUF_N) return;
  if (idx < OFF_B){                       // M[g][k][j] = sum_m W[k][m] * L[m][j]
    int g = idx >> 11; int r = idx & 2047; int k = r >> 6; int j = r & 63;
    const void* W = (g==0)?Wz:((g==1)?Wr:Wh);
    const void* L = (g==0)?Lz:((g==1)?Lr:Lh);
    float s = 0.f;
    for (int m=0;m<64;m++) s += ldf(W,k*64+m) * ldf(L,m*64+j);
    wbuf[idx] = s;
  } else if (idx < OFF_C){                // B[g][k][j] = L[(64+k)][j]
    int i = idx - OFF_B; int g = i >> 12; int r = i & 4095; int k = r >> 6; int j = r & 63;
    const void* L = (g==0)?Lz:((g==1)?Lr:Lh);
    wbuf[idx] = ldf(L,(64+k)*64 + j);
  } else if (idx < OFF_OW){               // c[g][j] = sum_m b[m]*L[m][j] + Lb[j]
    int i = idx - OFF_C; int g = i >> 6; int j = i & 63;
    const void* L  = (g==0)?Lz:((g==1)?Lr:Lh);
    const void* bb = (g==0)?bz:((g==1)?br:bh);
    const void* Lb = (g==0)?Lzb:((g==1)?Lrb:Lhb);
    float s = ldf(Lb,j);
    for (int m=0;m<64;m++) s += ldf(bb,m) * ldf(L,m*64+j);
    wbuf[idx] = s;
  } else if (idx < OFF_OB){
    wbuf[idx] = ldf(oW,idx - OFF_OW);
  } else {
    wbuf[idx] = ldf(ob,idx - OFF_OB);
  }
}

// ---------------- scatter into fixed slabs (no hist/scan prepass) ----------------
// slab for (t,b) at (t*NB+b)*CAP; bcur = cursors (pre-zeroed), end = counts
// packed entry: (dstlo << 16) | src
__global__ __launch_bounds__(256) void scatter_kernel(const int* __restrict__ ei,
                                                      int* __restrict__ bcur,
                                                      unsigned int* __restrict__ csrp){
  int t = blockIdx.y;
  __shared__ int cnt[NB];
  __shared__ int base[NB];
  int tid = threadIdx.x;
  cnt[tid] = 0;
  __syncthreads();
  int e0 = blockIdx.x*CHUNK;
  const int* srcs = ei + t*2*EE;
  const int* dsts = ei + t*2*EE + EE;
  int pk[CHUNK/256];        // (b<<12) | local_rank
  unsigned int pay[CHUNK/256];
  #pragma unroll
  for (int i = 0; i < CHUNK/256; i++){
    int e = e0 + i*256 + tid;
    if (e < EE){
      int s = srcs[e], d = dsts[e];
      int b = d / DPB;
      int lr = atomicAdd(&cnt[b], 1);
      pk[i] = (b << 12) | lr;
      pay[i] = ((unsigned)(d - b*DPB) << 16) | (unsigned)s;
    } else pk[i] = -1;
  }
  __syncthreads();
  if (cnt[tid] > 0) base[tid] = atomicAdd(&bcur[t*NB + tid], cnt[tid]);
  __syncthreads();
  #pragma unroll
  for (int i = 0; i < CHUNK/256; i++){
    if (pk[i] >= 0){
      int b = pk[i] >> 12, lr = pk[i] & 4095;
      int pos = base[b] + lr;
      if (pos < CAP) csrp[(size_t)(t*NB + b)*CAP + pos] = pay[i];
    }
  }
}

// ---------------- per-bucket degree -> dinv ----------------
__global__ __launch_bounds__(256) void degdinv_kernel(const unsigned int* __restrict__ csrp,
                                                      const int* __restrict__ bcur,
                                                      float* __restrict__ dinv){
  int b = blockIdx.x, t = blockIdx.y, tid = threadIdx.x;
  __shared__ int cnt[DPB];
  for (int i = tid; i < DPB; i += 256) cnt[i] = 0;
  __syncthreads();
  int ecnt = bcur[t*NB + b]; if (ecnt > CAP) ecnt = CAP;
  const unsigned int* cp = csrp + (size_t)(t*NB + b)*CAP;
  for (int i = tid; i < ecnt; i += 256)
    atomicAdd(&cnt[cp[i] >> 16], 1);
  __syncthreads();
  for (int i = tid; i < DPB; i += 256){
    int n = b*DPB + i;
    if (n < NN) dinv[t*NN + n] = rsqrtf((float)(cnt[i] + 1));  // +1 self loop
  }
}

// ---------------- bucket gather: counting-sort (int atomics) + register reduce --
// edges held in VGPRs between histogram and rank passes (single csrp read);
// self term from bf16 xb. agg[n][f] = dinv[n]*(dinv[n]*x[n][f] + sum dv[s]*x[s][f])
__global__ __launch_bounds__(256) void gatherb_kernel(const ushort_t* __restrict__ xb,
                                                      const float* __restrict__ dinv,
                                                      const unsigned int* __restrict__ csrp,
                                                      const int* __restrict__ bcur,
                                                      ushort_t* __restrict__ aggb){
  int b = blockIdx.x, t = blockIdx.y, tid = threadIdx.x;
  __shared__ ushort_t ssrc[SCAP];          // 16 KB: srcs sorted by dstlo
  __shared__ int cnt[DPB];
  __shared__ int off[DPB+1];
  __shared__ int wsum[4];
  for (int i = tid; i < DPB; i += 256) cnt[i] = 0;
  __syncthreads();
  int ecnt = bcur[t*NB + b]; if (ecnt > CAP) ecnt = CAP;
  const unsigned int* cp = csrp + (size_t)(t*NB + b)*CAP;
  unsigned pe[CAP/256]; int ne = 0;
  for (int e = tid; e < ecnt; e += 256){
    unsigned p = cp[e];
    pe[ne++] = p;
    atomicAdd(&cnt[p >> 16], 1);
  }
  __syncthreads();
  // exclusive scan cnt[0..195]
  int v = (tid < DPB) ? cnt[tid] : 0;
  int lane = tid & 63, wid = tid >> 6;
  int x = v;
  #pragma unroll
  for (int o = 1; o < 64; o <<= 1){
    int y = __shfl_up(x, o, 64);
    if (lane >= o) x += y;
  }
  if (lane == 63) wsum[wid] = x;
  __syncthreads();
  if (tid == 0){
    int s = 0;
    #pragma unroll
    for (int w = 0; w < 4; w++){ int tmp = wsum[w]; wsum[w] = s; s += tmp; }
  }
  __syncthreads();
  int excl = x - v + wsum[wid];
  if (tid < DPB){ off[tid] = excl; cnt[tid] = excl; }   // cnt becomes cursor
  if (tid == DPB-1) off[DPB] = excl + v;
  __syncthreads();
  for (int i = 0; i < ne; i++){
    unsigned p = pe[i];
    int r = atomicAdd(&cnt[p >> 16], 1);
    if (r < SCAP) ssrc[r] = (ushort_t)(p & 0xFFFFu);
  }
  __syncthreads();
  // register reduction: wave w owns dsts [w*49, w*49+49); 64 lanes = 2 edges x 32 f
  int w = tid >> 6;
  int eh = (tid >> 5) & 1;
  int f = tid & 31;
  const ushort_t* xbt = xb + (size_t)t*NN*FF;
  const float* dv = dinv + t*NN;
  for (int d = w*49; d < w*49 + 49; d++){
    int e0 = off[d], e1 = off[d+1];
    float accf = 0.f;
    int i = e0 + eh;
    int scur = (i < e1) ? (int)ssrc[i] : 0;
    while (i < e1){
      int inext = i + 2;
      int snxt = (inext < e1) ? (int)ssrc[inext] : 0;   // prefetch
      float dvs = dv[scur];
      float xv = ubf(xbt[(size_t)scur*FF + f]);
      accf += dvs * xv;
      i = inext; scur = snxt;
    }
    float sum = accf + __shfl_xor(accf, 32, 64);
    int n = b*DPB + d;
    if (eh == 0 && n < NN){
      float dn = dv[n];
      float sv = ubf(xbt[(size_t)n*FF + f]);             // self term from bf16
      aggb[((size_t)t*NN + n)*FF + f] = f2b(dn*(sum + dn*sv));
    }
  }
}

// ---------------- t=0 GRU step: h=0 -> h1 = (1-Z)*tanh(.), no h load/B-GEMMs ----
__global__ __launch_bounds__(256) void gate0_kernel(const ushort_t* __restrict__ aggt,
                                                    ushort_t* __restrict__ h,
                                                    const float* __restrict__ w){
  __shared__ float As[64][33];
  __shared__ float HRs[64][65];
  int tid = threadIdx.x;
  int nb = blockIdx.x*64;
  #pragma unroll
  for (int r = 0; r < 8; r++){
    int i = tid + 256*r; int n = i >> 5, k = i & 31; int gn = nb + n;
    As[n][k] = (gn < NN) ? ubf(aggt[gn*FF + k]) : 0.f;
  }
  __syncthreads();
  int node = tid & 63;
  int j0 = __builtin_amdgcn_readfirstlane((tid >> 6) * 16);
  float az[16], ah[16];
  #pragma unroll
  for (int jj = 0; jj < 16; jj++){
    az[jj] = w[OFF_C + j0 + jj];
    ah[jj] = w[OFF_C + 128 + j0 + jj];
  }
  #pragma unroll
  for (int k = 0; k < 32; k++){
    float a = As[node][k];
    const float* wz = w + OFF_M + k*64 + j0;
    const float* wh = w + OFF_M + 4096 + k*64 + j0;
    #pragma unroll
    for (int jj = 0; jj < 16; jj++){ az[jj] += a*wz[jj]; ah[jj] += a*wh[jj]; }
  }
  #pragma unroll
  for (int jj = 0; jj < 16; jj++){
    float z = 1.f / (1.f + __expf(-az[jj]));
    float xv = ah[jj];
    float e = __expf(-2.f * fabsf(xv));
    float th = (1.f - e) / (1.f + e);
    th = (xv < 0.f) ? -th : th;
    HRs[node][j0 + jj] = (1.f - z) * th;
  }
  __syncthreads();
  #pragma unroll
  for (int r = 0; r < 16; r++){
    int i = tid + 256*r; int n = i >> 6, k = i & 63; int gn = nb + n;
    if (gn < NN) h[gn*HH + k] = f2b(HRs[n][k]);
  }
}

// ---------------- GRU step t>=1 (h bf16); last step fuses out-projection --------
__global__ __launch_bounds__(256) void gate_kernel(const ushort_t* __restrict__ aggt,
                                                   ushort_t* __restrict__ h,
                                                   const float* __restrict__ w,
                                                   int last, float* __restrict__ out){
  __shared__ float As[64][33];
  __shared__ float Hs[64][65];
  __shared__ float HRs[64][65];
  int tid = threadIdx.x;
  int nb = blockIdx.x*64;
  #pragma unroll
  for (int r = 0; r < 8; r++){
    int i = tid + 256*r; int n = i >> 5, k = i & 31; int gn = nb + n;
    As[n][k] = (gn < NN) ? ubf(aggt[gn*FF + k]) : 0.f;
  }
  #pragma unroll
  for (int r = 0; r < 16; r++){
    int i = tid + 256*r; int n = i >> 6, k = i & 63; int gn = nb + n;
    Hs[n][k] = (gn < NN) ? ubf(h[gn*HH + k]) : 0.f;
  }
  __syncthreads();
  int node = tid & 63;
  int j0 = __builtin_amdgcn_readfirstlane((tid >> 6) * 16);

  // ---- R = sigmoid(agg@Mr + h@Br + cr); stage h*R ----
  float acc[16];
  #pragma unroll
  for (int jj = 0; jj < 16; jj++) acc[jj] = w[OFF_C + 64 + j0 + jj];
  #pragma unroll
  for (int k = 0; k < 32; k++){
    float a = As[node][k];
    const float* wr = w + OFF_M + 2048 + k*64 + j0;
    #pragma unroll
    for (int jj = 0; jj < 16; jj++) acc[jj] += a * wr[jj];
  }
  #pragma unroll
  for (int k = 0; k < 64; k++){
    float a = Hs[node][k];
    const float* wr = w + OFF_B + 4096 + k*64 + j0;
    #pragma unroll
    for (int jj = 0; jj < 16; jj++) acc[jj] += a * wr[jj];
  }
  #pragma unroll
  for (int jj = 0; jj < 16; jj++){
    float rr = 1.f / (1.f + __expf(-acc[jj]));
    HRs[node][j0 + jj] = Hs[node][j0 + jj] * rr;
  }
  __syncthreads();

  // ---- Z and Htilde ----
  float az[16], ah[16];
  #pragma unroll
  for (int jj = 0; jj < 16; jj++){
    az[jj] = w[OFF_C + j0 + jj];
    ah[jj] = w[OFF_C + 128 + j0 + jj];
  }
  #pragma unroll
  for (int k = 0; k < 32; k++){
    float a = As[node][k];
    const float* wz = w + OFF_M + k*64 + j0;
    const float* wh = w + OFF_M + 4096 + k*64 + j0;
    #pragma unroll
    for (int jj = 0; jj < 16; jj++){ az[jj] += a*wz[jj]; ah[jj] += a*wh[jj]; }
  }
  #pragma unroll
  for (int k = 0; k < 64; k++){
    float hk  = Hs[node][k];
    float hrk = HRs[node][k];
    const float* wz = w + OFF_B + k*64 + j0;
    const float* wh = w + OFF_B + 8192 + k*64 + j0;
    #pragma unroll
    for (int jj = 0; jj < 16; jj++){ az[jj] += hk*wz[jj]; ah[jj] += hrk*wh[jj]; }
  }
  float hnew[16];
  #pragma unroll
  for (int jj = 0; jj < 16; jj++){
    float z = 1.f / (1.f + __expf(-az[jj]));
    float xv = ah[jj];
    float e = __expf(-2.f * fabsf(xv));
    float th = (1.f - e) / (1.f + e);
    th = (xv < 0.f) ? -th : th;
    hnew[jj] = z * Hs[node][j0 + jj] + (1.f - z) * th;
  }
  __syncthreads();                          // all HRs reads done
  #pragma unroll
  for (int jj = 0; jj < 16; jj++) HRs[node][j0 + jj] = hnew[jj];
  __syncthreads();
  if (!last){
    #pragma unroll
    for (int r = 0; r < 16; r++){
      int i = tid + 256*r; int n = i >> 6, k = i & 63; int gn = nb + n;
      if (gn < NN) h[gn*HH + k] = f2b(HRs[n][k]);
    }
  } else {
    // fused out = hnew @ OW + ob; wave g handles outs [g*4, g*4+4)
    int g = tid >> 6;
    float o[4];
    #pragma unroll
    for (int oo = 0; oo < 4; oo++) o[oo] = w[OFF_OB + g*4 + oo];
    #pragma unroll
    for (int k = 0; k < 64; k++){
      float hk = HRs[node][k];
      const float* wr = w + OFF_OW + k*16 + g*4;
      #pragma unroll
      for (int oo = 0; oo < 4; oo++) o[oo] += hk * wr[oo];
    }
    int gn = nb + node;
    if (gn < NN){
      #pragma unroll
      for (int oo = 0; oo < 4; oo++) out[gn*OO + g*4 + oo] = o[oo];
    }
  }
}

extern "C" void kernel_launch(void* const* d_in, const int* in_sizes, int n_in,
                              void* d_out, int out_size, void* d_ws, size_t ws_size,
                              hipStream_t stream) {
  const float* xs = (const float*)d_in[0];
  const int*   ei = (const int*)d_in[1];
  float* out = (float*)d_out;
  char* ws = (char*)d_ws;
  // workspace layout (bytes); total ~71.25 MB (< round-6-proven 71.7 MB)
  ushort_t*     aggb = (ushort_t*)(ws + 0);              // 19,200,000
  ushort_t*     xb   = (ushort_t*)(ws + 19200000);       // 19,200,000
  unsigned int* csrp = (unsigned int*)(ws + 38400000);   // 256*6*4096*4 = 25,165,824
  ushort_t*     h    = (ushort_t*)(ws + 63565824);       //  6,400,000 (bf16)
  float*        dinv = (float*)(ws + 69965824);          //  1,200,000
  int*          bcur = (int*)  (ws + 71165824);          //  6,144
  float*        wbuf = (float*)(ws + 71171968);          //  78,656 -> end 71,250,624

  zero_kernel<<<2, 256, 0, stream>>>((uint4*)(ws + 71165824), 384);   // bcur
  cvt_kernel<<<(2400000 + 255)/256, 256, 0, stream>>>((const float4*)xs, (ushort4*)xb, 2400000);
  prep_kernel<<<(WBUF_N + 255)/256, 256, 0, stream>>>(d_in[2],d_in[3],d_in[4],d_in[5],
      d_in[6],d_in[7],d_in[8],d_in[9],d_in[10],d_in[11],d_in[12],d_in[13],d_in[14],d_in[15],
      wbuf);
  scatter_kernel<<<dim3((EE + CHUNK-1)/CHUNK, TT), 256, 0, stream>>>(ei, bcur, csrp);
  degdinv_kernel<<<dim3(NB, TT), 256, 0, stream>>>(csrp, bcur, dinv);
  gatherb_kernel<<<dim3(NB, TT), 256, 0, stream>>>(xb, dinv, csrp, bcur, aggb);
  gate0_kernel<<<(NN + 63)/64, 256, 0, stream>>>(aggb, h, wbuf);
  for (int t = 1; t < TT; t++)
    gate_kernel<<<(NN + 63)/64, 256, 0, stream>>>(aggb + (size_t)t*NN*FF, h, wbuf,
                                                  (t == TT-1) ? 1 : 0, out);
}

// Round 8
// 891.890 us; speedup vs baseline: 1.0651x; 1.0651x over previous
//
#include <hip/hip_runtime.h>
#include <hip/hip_bf16.h>

#define TT 6
#define NN 50000
#define EE 800000
#define FF 32
#define HH 64
#define OO 16

#define NB 256        // dst buckets
#define DPB 196       // dsts per bucket (256*196 = 50176 >= 50000)
#define CHUNK 4096    // edges per block in scatter
#define CAP 4096      // slab capacity per (t,bucket): mean 3125, sd 56 -> 17 sigma
#define SCAP 4096     // sorted-edge LDS capacity (== CAP)

// fused weight buffer layout (float offsets)
#define OFF_M 0        // M[g][32][64], g = z,r,h : W_g @ L_g[:64]
#define OFF_B 6144     // B[g][64][64]            : L_g[64:]
#define OFF_C 18432    // c[g][64]                : b_g @ L_g[:64] + L_g_b
#define OFF_OW 18624   // out_W [64][16]
#define OFF_OB 19648   // out_b [16]
#define WBUF_N 19664

typedef unsigned short ushort_t;
typedef unsigned char uchar_t;

__device__ __forceinline__ float ldf(const void* p, int i){ return ((const float*)p)[i]; }
__device__ __forceinline__ float ubf(ushort_t v){ return __uint_as_float(((unsigned)v) << 16); }
__device__ __forceinline__ ushort_t f2b(float f){
  unsigned u = __float_as_uint(f);
  return (ushort_t)((u + 0x7FFFu + ((u >> 16) & 1u)) >> 16);
}

// ---------------- zero ----------------
__global__ void zero_kernel(uint4* __restrict__ p, int n4){
  int i = blockIdx.x*256 + threadIdx.x;
  if (i < n4) p[i] = make_uint4(0,0,0,0);
}

// ---------------- f32 -> bf16 convert (xs -> xb) ----------------
__global__ void cvt_kernel(const float4* __restrict__ x, ushort4* __restrict__ xb, int n4){
  int i = blockIdx.x*256 + threadIdx.x;
  if (i < n4){
    float4 v = x[i];
    ushort4 o;
    o.x = f2b(v.x); o.y = f2b(v.y); o.z = f2b(v.z); o.w = f2b(v.w);
    xb[i] = o;
  }
}

// ---------------- fused-weight prep (all inputs f32) ----------------
__global__ void prep_kernel(const void* Wz,const void* bz,const void* Wr,const void* br,
                            const void* Wh,const void* bh,
                            const void* Lz,const void* Lzb,const void* Lr,const void* Lrb,
                            const void* Lh,const void* Lhb,
                            const void* oW,const void* ob, float* __restrict__ wbuf){
  int idx = blockIdx.x*256 + threadIdx.x;
  if (idx >= WBUF_N) return;
  if (idx < OFF_B){                       // M[g][k][j] = sum_m W[k][m] * L[m][j]
    int g = idx >> 11; int r = idx & 2047; int k = r >> 6; int j = r & 63;
    const void* W = (g==0)?Wz:((g==1)?Wr:Wh);
    const void* L = (g==0)?Lz:((g==1)?Lr:Lh);
    float s = 0.f;
    for (int m=0;m<64;m++) s += ldf(W,k*64+m) * ldf(L,m*64+j);
    wbuf[idx] = s;
  } else if (idx < OFF_C){                // B[g][k][j] = L[(64+k)][j]
    int i = idx - OFF_B; int g = i >> 12; int r = i & 4095; int k = r >> 6; int j = r & 63;
    const void* L = (g==0)?Lz:((g==1)?Lr:Lh);
    wbuf[idx] = ldf(L,(64+k)*64 + j);
  } else if (idx < OFF_OW){               // c[g][j] = sum_m b[m]*L[m][j] + Lb[j]
    int i = idx - OFF_C; int g = i >> 6; int j = i & 63;
    const void* L  = (g==0)?Lz:((g==1)?Lr:Lh);
    const void* bb = (g==0)?bz:((g==1)?br:bh);
    const void* Lb = (g==0)?Lzb:((g==1)?Lrb:Lhb);
    float s = ldf(Lb,j);
    for (int m=0;m<64;m++) s += ldf(bb,m) * ldf(L,m*64+j);
    wbuf[idx] = s;
  } else if (idx < OFF_OB){
    wbuf[idx] = ldf(oW,idx - OFF_OW);
  } else {
    wbuf[idx] = ldf(ob,idx - OFF_OB);
  }
}

// ---------------- scatter: LDS counting-sort by bucket -> coalesced slab writes --
// SoA slabs: ssrc16[(t*NB+b)*CAP] (u16 src), sdst8[...] (u8 dstlo)
__global__ __launch_bounds__(256) void scatter_kernel(const int* __restrict__ ei,
                                                      int* __restrict__ bcur,
                                                      ushort_t* __restrict__ ssrc16,
                                                      uchar_t* __restrict__ sdst8){
  int t = blockIdx.y;
  __shared__ int cnt[NB];
  __shared__ int lstart[NB];
  __shared__ int gbase[NB];
  __shared__ int wsum[4];
  __shared__ ushort_t spay[CHUNK];   // 8 KB src sorted by bucket
  __shared__ uchar_t  sdlo[CHUNK];   // 4 KB dstlo sorted
  __shared__ uchar_t  sbk[CHUNK];    // 4 KB bucket id per sorted slot
  int tid = threadIdx.x;
  cnt[tid] = 0;
  __syncthreads();
  int e0 = blockIdx.x*CHUNK;
  const int* srcs = ei + t*2*EE;
  const int* dsts = ei + t*2*EE + EE;
  int pk[CHUNK/256];   // (b<<12) | local_rank, -1 = invalid
  int ps[CHUNK/256];
  int pd[CHUNK/256];
  #pragma unroll
  for (int i = 0; i < CHUNK/256; i++){
    int e = e0 + i*256 + tid;
    if (e < EE){
      int s = srcs[e], d = dsts[e];
      int b = d / DPB;
      int lr = atomicAdd(&cnt[b], 1);
      pk[i] = (b << 12) | lr;
      ps[i] = s;
      pd[i] = d - b*DPB;
    } else pk[i] = -1;
  }
  __syncthreads();
  // exclusive scan cnt -> lstart; reserve global runs
  {
    int v = cnt[tid];
    int lane = tid & 63, wid = tid >> 6;
    int x = v;
    #pragma unroll
    for (int o = 1; o < 64; o <<= 1){
      int y = __shfl_up(x, o, 64);
      if (lane >= o) x += y;
    }
    if (lane == 63) wsum[wid] = x;
    __syncthreads();
    if (tid == 0){
      int s = 0;
      #pragma unroll
      for (int w = 0; w < 4; w++){ int tmp = wsum[w]; wsum[w] = s; s += tmp; }
    }
    __syncthreads();
    lstart[tid] = x - v + wsum[wid];
    gbase[tid] = (v > 0) ? atomicAdd(&bcur[t*NB + tid], v) : 0;
  }
  __syncthreads();
  // sorted store into LDS
  #pragma unroll
  for (int i = 0; i < CHUNK/256; i++){
    if (pk[i] >= 0){
      int b = pk[i] >> 12, lr = pk[i] & 4095;
      int pos = lstart[b] + lr;
      spay[pos] = (ushort_t)ps[i];
      sdlo[pos] = (uchar_t)pd[i];
      sbk[pos]  = (uchar_t)b;
    }
  }
  __syncthreads();
  // coalesced global writes: consecutive i within a bucket -> consecutive slab pos
  int nE = EE - e0; if (nE > CHUNK) nE = CHUNK;
  for (int i = tid; i < nE; i += 256){
    int b = sbk[i];
    int gpos = gbase[b] + (i - lstart[b]);
    if (gpos < CAP){
      size_t sb = (size_t)(t*NB + b)*CAP + gpos;
      ssrc16[sb] = spay[i];
      sdst8[sb]  = sdlo[i];
    }
  }
}

// ---------------- per-bucket degree -> dinv (reads u8 slab only) ----------------
__global__ __launch_bounds__(256) void degdinv_kernel(const uchar_t* __restrict__ sdst8,
                                                      const int* __restrict__ bcur,
                                                      float* __restrict__ dinv){
  int b = blockIdx.x, t = blockIdx.y, tid = threadIdx.x;
  __shared__ int cnt[DPB];
  for (int i = tid; i < DPB; i += 256) cnt[i] = 0;
  __syncthreads();
  int ecnt = bcur[t*NB + b]; if (ecnt > CAP) ecnt = CAP;
  const uchar_t* dp = sdst8 + (size_t)(t*NB + b)*CAP;
  for (int i = tid; i < ecnt; i += 256)
    atomicAdd(&cnt[dp[i]], 1);
  __syncthreads();
  for (int i = tid; i < DPB; i += 256){
    int n = b*DPB + i;
    if (n < NN) dinv[t*NN + n] = rsqrtf((float)(cnt[i] + 1));  // +1 self loop
  }
}

// ---------------- bucket gather: counting-sort (int atomics) + register reduce --
__global__ __launch_bounds__(256) void gatherb_kernel(const ushort_t* __restrict__ xb,
                                                      const float* __restrict__ dinv,
                                                      const ushort_t* __restrict__ ssrc16,
                                                      const uchar_t* __restrict__ sdst8,
                                                      const int* __restrict__ bcur,
                                                      ushort_t* __restrict__ aggb){
  int b = blockIdx.x, t = blockIdx.y, tid = threadIdx.x;
  __shared__ ushort_t ssrc[SCAP];          // 8 KB srcs sorted by dstlo
  __shared__ int cnt[DPB];
  __shared__ int off[DPB+1];
  __shared__ int wsum[4];
  for (int i = tid; i < DPB; i += 256) cnt[i] = 0;
  __syncthreads();
  int ecnt = bcur[t*NB + b]; if (ecnt > CAP) ecnt = CAP;
  size_t slab = (size_t)(t*NB + b)*CAP;
  const ushort_t* sp = ssrc16 + slab;
  const uchar_t*  dp = sdst8 + slab;
  unsigned pe[CAP/256]; int ne = 0;        // (dlo<<16)|src held in VGPRs
  for (int e = tid; e < ecnt; e += 256){
    unsigned s = sp[e];
    unsigned dlo = dp[e];
    pe[ne++] = (dlo << 16) | s;
    atomicAdd(&cnt[dlo], 1);
  }
  __syncthreads();
  // exclusive scan cnt[0..195]
  int v = (tid < DPB) ? cnt[tid] : 0;
  int lane = tid & 63, wid = tid >> 6;
  int x = v;
  #pragma unroll
  for (int o = 1; o < 64; o <<= 1){
    int y = __shfl_up(x, o, 64);
    if (lane >= o) x += y;
  }
  if (lane == 63) wsum[wid] = x;
  __syncthreads();
  if (tid == 0){
    int s = 0;
    #pragma unroll
    for (int w = 0; w < 4; w++){ int tmp = wsum[w]; wsum[w] = s; s += tmp; }
  }
  __syncthreads();
  int excl = x - v + wsum[wid];
  if (tid < DPB){ off[tid] = excl; cnt[tid] = excl; }   // cnt becomes cursor
  if (tid == DPB-1) off[DPB] = excl + v;
  __syncthreads();
  for (int i = 0; i < ne; i++){
    unsigned p = pe[i];
    int r = atomicAdd(&cnt[p >> 16], 1);
    if (r < SCAP) ssrc[r] = (ushort_t)(p & 0xFFFFu);
  }
  __syncthreads();
  // register reduction: wave w owns dsts [w*49, w*49+49); 64 lanes = 2 edges x 32 f
  int w = tid >> 6;
  int eh = (tid >> 5) & 1;
  int f = tid & 31;
  const ushort_t* xbt = xb + (size_t)t*NN*FF;
  const float* dv = dinv + t*NN;
  for (int d = w*49; d < w*49 + 49; d++){
    int e0 = off[d], e1 = off[d+1];
    float accf = 0.f;
    int i = e0 + eh;
    int scur = (i < e1) ? (int)ssrc[i] : 0;
    while (i < e1){
      int inext = i + 2;
      int snxt = (inext < e1) ? (int)ssrc[inext] : 0;   // prefetch
      float dvs = dv[scur];
      float xv = ubf(xbt[(size_t)scur*FF + f]);
      accf += dvs * xv;
      i = inext; scur = snxt;
    }
    float sum = accf + __shfl_xor(accf, 32, 64);
    int n = b*DPB + d;
    if (eh == 0 && n < NN){
      float dn = dv[n];
      float sv = ubf(xbt[(size_t)n*FF + f]);             // self term
      aggb[((size_t)t*NN + n)*FF + f] = f2b(dn*(sum + dn*sv));
    }
  }
}

// ---------------- ALL GRU steps fused: h LDS-resident across t; out fused -------
__global__ __launch_bounds__(256) void gates_kernel(const ushort_t* __restrict__ aggb,
                                                    const float* __restrict__ w,
                                                    float* __restrict__ out){
  __shared__ float As[64][33];
  __shared__ float Hs[64][65];
  __shared__ float HRs[64][65];
  int tid = threadIdx.x;
  int nb = blockIdx.x*64;
  #pragma unroll
  for (int r = 0; r < 16; r++){
    int i = tid + 256*r;
    Hs[i >> 6][i & 63] = 0.f;
  }
  int node = tid & 63;
  int j0 = __builtin_amdgcn_readfirstlane((tid >> 6) * 16);  // wave-uniform
  for (int t = 0; t < TT; t++){
    const ushort_t* aggt = aggb + (size_t)t*NN*FF;
    #pragma unroll
    for (int r = 0; r < 8; r++){
      int i = tid + 256*r; int n = i >> 5, k = i & 31; int gn = nb + n;
      As[n][k] = (gn < NN) ? ubf(aggt[gn*FF + k]) : 0.f;
    }
    __syncthreads();     // As ready; also orders prev-iter Hs writes
    if (t > 0){
      // ---- R = sigmoid(agg@Mr + h@Br + cr); stage h*R ----
      float acc[16];
      #pragma unroll
      for (int jj = 0; jj < 16; jj++) acc[jj] = w[OFF_C + 64 + j0 + jj];
      #pragma unroll
      for (int k = 0; k < 32; k++){
        float a = As[node][k];
        const float* wr = w + OFF_M + 2048 + k*64 + j0;
        #pragma unroll
        for (int jj = 0; jj < 16; jj++) acc[jj] += a * wr[jj];
      }
      #pragma unroll
      for (int k = 0; k < 64; k++){
        float a = Hs[node][k];
        const float* wr = w + OFF_B + 4096 + k*64 + j0;
        #pragma unroll
        for (int jj = 0; jj < 16; jj++) acc[jj] += a * wr[jj];
      }
      #pragma unroll
      for (int jj = 0; jj < 16; jj++){
        float rr = 1.f / (1.f + __expf(-acc[jj]));
        HRs[node][j0 + jj] = Hs[node][j0 + jj] * rr;
      }
      __syncthreads();
    }
    // ---- Z and Htilde ----
    float az[16], ah[16];
    #pragma unroll
    for (int jj = 0; jj < 16; jj++){
      az[jj] = w[OFF_C + j0 + jj];
      ah[jj] = w[OFF_C + 128 + j0 + jj];
    }
    #pragma unroll
    for (int k = 0; k < 32; k++){
      float a = As[node][k];
      const float* wz = w + OFF_M + k*64 + j0;
      const float* wh = w + OFF_M + 4096 + k*64 + j0;
      #pragma unroll
      for (int jj = 0; jj < 16; jj++){ az[jj] += a*wz[jj]; ah[jj] += a*wh[jj]; }
    }
    if (t > 0){
      #pragma unroll
      for (int k = 0; k < 64; k++){
        float hk  = Hs[node][k];
        float hrk = HRs[node][k];
        const float* wz = w + OFF_B + k*64 + j0;
        const float* wh = w + OFF_B + 8192 + k*64 + j0;
        #pragma unroll
        for (int jj = 0; jj < 16; jj++){ az[jj] += hk*wz[jj]; ah[jj] += hrk*wh[jj]; }
      }
    }
    float hnew[16];
    #pragma unroll
    for (int jj = 0; jj < 16; jj++){
      float z = 1.f / (1.f + __expf(-az[jj]));
      float xv = ah[jj];
      float e = __expf(-2.f * fabsf(xv));
      float th = (1.f - e) / (1.f + e);
      th = (xv < 0.f) ? -th : th;
      hnew[jj] = z * Hs[node][j0 + jj] + (1.f - z) * th;
    }
    __syncthreads();     // all reads of Hs/HRs complete before overwrite
    #pragma unroll
    for (int jj = 0; jj < 16; jj++) Hs[node][j0 + jj] = hnew[jj];
  }
  __syncthreads();
  // ---- fused out = h @ OW + ob; wave g handles outs [g*4, g*4+4) ----
  int g = tid >> 6;
  float o[4];
  #pragma unroll
  for (int oo = 0; oo < 4; oo++) o[oo] = w[OFF_OB + g*4 + oo];
  #pragma unroll
  for (int k = 0; k < 64; k++){
    float hk = Hs[node][k];
    const float* wr = w + OFF_OW + k*16 + g*4;
    #pragma unroll
    for (int oo = 0; oo < 4; oo++) o[oo] += hk * wr[oo];
  }
  int gn = nb + node;
  if (gn < NN){
    #pragma unroll
    for (int oo = 0; oo < 4; oo++) out[gn*OO + g*4 + oo] = o[oo];
  }
}

extern "C" void kernel_launch(void* const* d_in, const int* in_sizes, int n_in,
                              void* d_out, int out_size, void* d_ws, size_t ws_size,
                              hipStream_t stream) {
  const float* xs = (const float*)d_in[0];
  const int*   ei = (const int*)d_in[1];
  float* out = (float*)d_out;
  char* ws = (char*)d_ws;
  // workspace layout (bytes); total ~58.6 MB
  ushort_t*  aggb   = (ushort_t*)(ws + 0);           // 19,200,000
  ushort_t*  xb     = (ushort_t*)(ws + 19200000);    // 19,200,000
  ushort_t*  ssrc16 = (ushort_t*)(ws + 38400000);    // 6*256*4096*2 = 12,582,912
  uchar_t*   sdst8  = (uchar_t*) (ws + 50982912);    // 6*256*4096   =  6,291,456
  float*     dinv   = (float*)   (ws + 57274368);    //  1,200,000
  int*       bcur   = (int*)     (ws + 58474368);    //  6,144
  float*     wbuf   = (float*)   (ws + 58480512);    //  78,656 -> end 58,559,168

  zero_kernel<<<2, 256, 0, stream>>>((uint4*)(ws + 58474368), 384);   // bcur
  cvt_kernel<<<(2400000 + 255)/256, 256, 0, stream>>>((const float4*)xs, (ushort4*)xb, 2400000);
  prep_kernel<<<(WBUF_N + 255)/256, 256, 0, stream>>>(d_in[2],d_in[3],d_in[4],d_in[5],
      d_in[6],d_in[7],d_in[8],d_in[9],d_in[10],d_in[11],d_in[12],d_in[13],d_in[14],d_in[15],
      wbuf);
  scatter_kernel<<<dim3((EE + CHUNK-1)/CHUNK, TT), 256, 0, stream>>>(ei, bcur, ssrc16, sdst8);
  degdinv_kernel<<<dim3(NB, TT), 256, 0, stream>>>(sdst8, bcur, dinv);
  gatherb_kernel<<<dim3(NB, TT), 256, 0, stream>>>(xb, dinv, ssrc16, sdst8, bcur, aggb);
  gates_kernel<<<(NN + 63)/64, 256, 0, stream>>>(aggb, wbuf, out);
}

// Round 9
// 412.661 us; speedup vs baseline: 2.3019x; 2.1613x over previous
//
#include <hip/hip_runtime.h>
#include <hip/hip_bf16.h>

#define TT 6
#define NN 50000
#define EE 800000
#define FF 32
#define HH 64
#define OO 16

#define NB 256        // dst buckets
#define DPB 196       // dsts per bucket (256*196 = 50176 >= 50000)
#define CHUNK 4096    // edges per block in scatter
#define CAP 4096      // slab capacity per (t,bucket): mean 3125, sd 56 -> 17 sigma
#define SCAP 4096     // sorted-edge LDS capacity (== CAP)

// fused weight buffer layout (float offsets)
#define OFF_M 0        // M[g][32][64], g = z,r,h : W_g @ L_g[:64]
#define OFF_B 6144     // B[g][64][64]            : L_g[64:]
#define OFF_C 18432    // c[g][64]                : b_g @ L_g[:64] + L_g_b
#define OFF_OW 18624   // out_W [64][16]
#define OFF_OB 19648   // out_b [16]
#define WBUF_N 19664
#define WFRAG_N 19456  // 38 slots * 512 bf16 fragment-packed weights

typedef unsigned short ushort_t;
typedef unsigned char uchar_t;
typedef short short8 __attribute__((ext_vector_type(8)));   // 8 bf16 (4 VGPRs)
typedef float f32x4 __attribute__((ext_vector_type(4)));

__device__ __forceinline__ float ldf(const void* p, int i){ return ((const float*)p)[i]; }
__device__ __forceinline__ float ubf(ushort_t v){ return __uint_as_float(((unsigned)v) << 16); }
__device__ __forceinline__ ushort_t f2b(float f){
  unsigned u = __float_as_uint(f);
  return (ushort_t)((u + 0x7FFFu + ((u >> 16) & 1u)) >> 16);
}

// ---------------- zero ----------------
__global__ void zero_kernel(uint4* __restrict__ p, int n4){
  int i = blockIdx.x*256 + threadIdx.x;
  if (i < n4) p[i] = make_uint4(0,0,0,0);
}

// ---------------- f32 -> bf16 convert (xs -> xb) ----------------
__global__ void cvt_kernel(const float4* __restrict__ x, ushort4* __restrict__ xb, int n4){
  int i = blockIdx.x*256 + threadIdx.x;
  if (i < n4){
    float4 v = x[i];
    ushort4 o;
    o.x = f2b(v.x); o.y = f2b(v.y); o.z = f2b(v.z); o.w = f2b(v.w);
    xb[i] = o;
  }
}

// ---------------- fused-weight prep (all inputs f32) ----------------
__global__ void prep_kernel(const void* Wz,const void* bz,const void* Wr,const void* br,
                            const void* Wh,const void* bh,
                            const void* Lz,const void* Lzb,const void* Lr,const void* Lrb,
                            const void* Lh,const void* Lhb,
                            const void* oW,const void* ob, float* __restrict__ wbuf){
  int idx = blockIdx.x*256 + threadIdx.x;
  if (idx >= WBUF_N) return;
  if (idx < OFF_B){                       // M[g][k][j] = sum_m W[k][m] * L[m][j]
    int g = idx >> 11; int r = idx & 2047; int k = r >> 6; int j = r & 63;
    const void* W = (g==0)?Wz:((g==1)?Wr:Wh);
    const void* L = (g==0)?Lz:((g==1)?Lr:Lh);
    float s = 0.f;
    for (int m=0;m<64;m++) s += ldf(W,k*64+m) * ldf(L,m*64+j);
    wbuf[idx] = s;
  } else if (idx < OFF_C){                // B[g][k][j] = L[(64+k)][j]
    int i = idx - OFF_B; int g = i >> 12; int r = i & 4095; int k = r >> 6; int j = r & 63;
    const void* L = (g==0)?Lz:((g==1)?Lr:Lh);
    wbuf[idx] = ldf(L,(64+k)*64 + j);
  } else if (idx < OFF_OW){               // c[g][j] = sum_m b[m]*L[m][j] + Lb[j]
    int i = idx - OFF_C; int g = i >> 6; int j = i & 63;
    const void* L  = (g==0)?Lz:((g==1)?Lr:Lh);
    const void* bb = (g==0)?bz:((g==1)?br:bh);
    const void* Lb = (g==0)?Lzb:((g==1)?Lrb:Lhb);
    float s = ldf(Lb,j);
    for (int m=0;m<64;m++) s += ldf(bb,m) * ldf(L,m*64+j);
    wbuf[idx] = s;
  } else if (idx < OFF_OB){
    wbuf[idx] = ldf(oW,idx - OFF_OW);
  } else {
    wbuf[idx] = ldf(ob,idx - OFF_OB);
  }
}

// ---------------- weight fragment packing (B-operand layout, bf16) ----------------
// slot 0..23: GEMM1 (nt 0..7 over [Z|R] cols, kc 0..2 over K=96=[A32|H64])
// slot 24..35: GEMM2 (nt 0..3 over Ht cols). slot 36..37: out-proj (K=64).
// element: wfrag[(slot*64 + lane)*8 + j] = W[k = kc*32 + (lane>>4)*8 + j][n = nt*16 + (lane&15)]
__global__ void prep2_kernel(const float* __restrict__ wbuf, short* __restrict__ wfrag){
  int idx = blockIdx.x*256 + threadIdx.x;   // 0..19455
  if (idx >= WFRAG_N) return;
  int slot = idx >> 9;
  int lane = (idx >> 3) & 63;
  int j = idx & 7;
  int q = lane >> 4, l15 = lane & 15;
  float val;
  if (slot < 24){
    int nt = slot/3, kc = slot - nt*3;
    int ncol = nt*16 + l15;          // 0..127 (Z then R)
    int k = kc*32 + q*8 + j;         // 0..95
    int g = (ncol < 64) ? 0 : 1;
    int jin = ncol & 63;
    val = (k < 32) ? wbuf[OFF_M + g*2048 + k*64 + jin]
                   : wbuf[OFF_B + g*4096 + (k-32)*64 + jin];
  } else if (slot < 36){
    int s2 = slot - 24;
    int nt = s2/3, kc = s2 - nt*3;
    int ncol = nt*16 + l15;          // 0..63
    int k = kc*32 + q*8 + j;
    val = (k < 32) ? wbuf[OFF_M + 2*2048 + k*64 + ncol]
                   : wbuf[OFF_B + 2*4096 + (k-32)*64 + ncol];
  } else {
    int kc = slot - 36;
    int k = kc*32 + q*8 + j;         // 0..63
    val = wbuf[OFF_OW + k*16 + l15];
  }
  wfrag[idx] = (short)f2b(val);
}

// ---------------- scatter: LDS counting-sort by bucket -> coalesced slab writes --
__global__ __launch_bounds__(256) void scatter_kernel(const int* __restrict__ ei,
                                                      int* __restrict__ bcur,
                                                      ushort_t* __restrict__ ssrc16,
                                                      uchar_t* __restrict__ sdst8){
  int t = blockIdx.y;
  __shared__ int cnt[NB];
  __shared__ int lstart[NB];
  __shared__ int gbase[NB];
  __shared__ int wsum[4];
  __shared__ ushort_t spay[CHUNK];
  __shared__ uchar_t  sdlo[CHUNK];
  __shared__ uchar_t  sbk[CHUNK];
  int tid = threadIdx.x;
  cnt[tid] = 0;
  __syncthreads();
  int e0 = blockIdx.x*CHUNK;
  const int* srcs = ei + t*2*EE;
  const int* dsts = ei + t*2*EE + EE;
  int pk[CHUNK/256];
  int ps[CHUNK/256];
  int pd[CHUNK/256];
  #pragma unroll
  for (int i = 0; i < CHUNK/256; i++){
    int e = e0 + i*256 + tid;
    if (e < EE){
      int s = srcs[e], d = dsts[e];
      int b = d / DPB;
      int lr = atomicAdd(&cnt[b], 1);
      pk[i] = (b << 12) | lr;
      ps[i] = s;
      pd[i] = d - b*DPB;
    } else pk[i] = -1;
  }
  __syncthreads();
  {
    int v = cnt[tid];
    int lane = tid & 63, wid = tid >> 6;
    int x = v;
    #pragma unroll
    for (int o = 1; o < 64; o <<= 1){
      int y = __shfl_up(x, o, 64);
      if (lane >= o) x += y;
    }
    if (lane == 63) wsum[wid] = x;
    __syncthreads();
    if (tid == 0){
      int s = 0;
      #pragma unroll
      for (int w = 0; w < 4; w++){ int tmp = wsum[w]; wsum[w] = s; s += tmp; }
    }
    __syncthreads();
    lstart[tid] = x - v + wsum[wid];
    gbase[tid] = (v > 0) ? atomicAdd(&bcur[t*NB + tid], v) : 0;
  }
  __syncthreads();
  #pragma unroll
  for (int i = 0; i < CHUNK/256; i++){
    if (pk[i] >= 0){
      int b = pk[i] >> 12, lr = pk[i] & 4095;
      int pos = lstart[b] + lr;
      spay[pos] = (ushort_t)ps[i];
      sdlo[pos] = (uchar_t)pd[i];
      sbk[pos]  = (uchar_t)b;
    }
  }
  __syncthreads();
  int nE = EE - e0; if (nE > CHUNK) nE = CHUNK;
  for (int i = tid; i < nE; i += 256){
    int b = sbk[i];
    int gpos = gbase[b] + (i - lstart[b]);
    if (gpos < CAP){
      size_t sb = (size_t)(t*NB + b)*CAP + gpos;
      ssrc16[sb] = spay[i];
      sdst8[sb]  = sdlo[i];
    }
  }
}

// ---------------- per-bucket degree -> dinv (reads u8 slab only) ----------------
__global__ __launch_bounds__(256) void degdinv_kernel(const uchar_t* __restrict__ sdst8,
                                                      const int* __restrict__ bcur,
                                                      float* __restrict__ dinv){
  int b = blockIdx.x, t = blockIdx.y, tid = threadIdx.x;
  __shared__ int cnt[DPB];
  for (int i = tid; i < DPB; i += 256) cnt[i] = 0;
  __syncthreads();
  int ecnt = bcur[t*NB + b]; if (ecnt > CAP) ecnt = CAP;
  const uchar_t* dp = sdst8 + (size_t)(t*NB + b)*CAP;
  for (int i = tid; i < ecnt; i += 256)
    atomicAdd(&cnt[dp[i]], 1);
  __syncthreads();
  for (int i = tid; i < DPB; i += 256){
    int n = b*DPB + i;
    if (n < NN) dinv[t*NN + n] = rsqrtf((float)(cnt[i] + 1));  // +1 self loop
  }
}

// ---------------- bucket gather: counting-sort (int atomics) + register reduce --
__global__ __launch_bounds__(256) void gatherb_kernel(const ushort_t* __restrict__ xb,
                                                      const float* __restrict__ dinv,
                                                      const ushort_t* __restrict__ ssrc16,
                                                      const uchar_t* __restrict__ sdst8,
                                                      const int* __restrict__ bcur,
                                                      ushort_t* __restrict__ aggb){
  int b = blockIdx.x, t = blockIdx.y, tid = threadIdx.x;
  __shared__ ushort_t ssrc[SCAP];
  __shared__ int cnt[DPB];
  __shared__ int off[DPB+1];
  __shared__ int wsum[4];
  for (int i = tid; i < DPB; i += 256) cnt[i] = 0;
  __syncthreads();
  int ecnt = bcur[t*NB + b]; if (ecnt > CAP) ecnt = CAP;
  size_t slab = (size_t)(t*NB + b)*CAP;
  const ushort_t* sp = ssrc16 + slab;
  const uchar_t*  dp = sdst8 + slab;
  unsigned pe[CAP/256]; int ne = 0;
  for (int e = tid; e < ecnt; e += 256){
    unsigned s = sp[e];
    unsigned dlo = dp[e];
    pe[ne++] = (dlo << 16) | s;
    atomicAdd(&cnt[dlo], 1);
  }
  __syncthreads();
  int v = (tid < DPB) ? cnt[tid] : 0;
  int lane = tid & 63, wid = tid >> 6;
  int x = v;
  #pragma unroll
  for (int o = 1; o < 64; o <<= 1){
    int y = __shfl_up(x, o, 64);
    if (lane >= o) x += y;
  }
  if (lane == 63) wsum[wid] = x;
  __syncthreads();
  if (tid == 0){
    int s = 0;
    #pragma unroll
    for (int w = 0; w < 4; w++){ int tmp = wsum[w]; wsum[w] = s; s += tmp; }
  }
  __syncthreads();
  int excl = x - v + wsum[wid];
  if (tid < DPB){ off[tid] = excl; cnt[tid] = excl; }
  if (tid == DPB-1) off[DPB] = excl + v;
  __syncthreads();
  for (int i = 0; i < ne; i++){
    unsigned p = pe[i];
    int r = atomicAdd(&cnt[p >> 16], 1);
    if (r < SCAP) ssrc[r] = (ushort_t)(p & 0xFFFFu);
  }
  __syncthreads();
  int w = tid >> 6;
  int eh = (tid >> 5) & 1;
  int f = tid & 31;
  const ushort_t* xbt = xb + (size_t)t*NN*FF;
  const float* dv = dinv + t*NN;
  for (int d = w*49; d < w*49 + 49; d++){
    int e0 = off[d], e1 = off[d+1];
    float accf = 0.f;
    int i = e0 + eh;
    int scur = (i < e1) ? (int)ssrc[i] : 0;
    while (i < e1){
      int inext = i + 2;
      int snxt = (inext < e1) ? (int)ssrc[inext] : 0;
      float dvs = dv[scur];
      float xv = ubf(xbt[(size_t)scur*FF + f]);
      accf += dvs * xv;
      i = inext; scur = snxt;
    }
    float sum = accf + __shfl_xor(accf, 32, 64);
    int n = b*DPB + d;
    if (eh == 0 && n < NN){
      float dn = dv[n];
      float sv = ubf(xbt[(size_t)n*FF + f]);
      aggb[((size_t)t*NN + n)*FF + f] = f2b(dn*(sum + dn*sv));
    }
  }
}

// ---------------- ALL GRU steps, MFMA version; h LDS-resident; out fused --------
// Block = 64 nodes, 4 waves. Wave wv owns j-cols [16wv,16wv+16) for Z,R,Ht,h-update.
// LDS matrices in chunk-packed layout: elem(m,k) at ((k>>3)*64+m)*8+(k&7).
__global__ __launch_bounds__(256) void gates_kernel(const ushort_t* __restrict__ aggb,
                                                    const float* __restrict__ w,
                                                    const short* __restrict__ wfrag,
                                                    float* __restrict__ out){
  __shared__ __align__(16) short As[2048];    // 64 x 32  (4 KB)
  __shared__ __align__(16) short Hsp[4096];   // 64 x 64  (8 KB)
  __shared__ __align__(16) short HRp[4096];   // 64 x 64  (8 KB)
  int tid = threadIdx.x;
  int nb = blockIdx.x*64;
  int wv = tid >> 6, lane = tid & 63;
  int q = lane >> 4, l15 = lane & 15;
  #pragma unroll
  for (int r = 0; r < 8; r++) ((int*)Hsp)[tid + 256*r] = 0;
  // persistent weight fragments (B-operand): 36 VGPRs
  short8 wz[3], wr[3], wh[3];
  #pragma unroll
  for (int kc = 0; kc < 3; kc++){
    wz[kc] = ((const short8*)wfrag)[(wv*3 + kc)*64 + lane];
    wr[kc] = ((const short8*)wfrag)[((wv+4)*3 + kc)*64 + lane];
    wh[kc] = ((const short8*)wfrag)[(24 + wv*3 + kc)*64 + lane];
  }
  int jz = wv*16 + l15;
  float cz = w[OFF_C + jz], cr = w[OFF_C + 64 + jz], ch = w[OFF_C + 128 + jz];
  int hidx = ((jz >> 3)*64)*8 + (jz & 7);     // scalar base for col jz (add node*8)
  f32x4 accZ[4], accR[4];
  for (int t = 0; t < TT; t++){
    { // stage A(t) -> LDS packed
      int n = tid >> 2, c = tid & 3, gn = nb + n;
      uint4 v = make_uint4(0,0,0,0);
      if (gn < NN) v = ((const uint4*)aggb)[((size_t)t*NN + gn)*4 + (size_t)c];
      *(uint4*)&As[(c*64 + n)*8] = v;
    }
    __syncthreads();                          // A ready; Hsp(t-1) writes visible
    // ---- GEMM1: [A|H] @ [Wz|Wr] ----
    #pragma unroll
    for (int mt = 0; mt < 4; mt++){
      short8 fa  = *(const short8*)&As [((q)*64   + mt*16 + l15)*8];
      short8 fh0 = *(const short8*)&Hsp[((q)*64   + mt*16 + l15)*8];
      short8 fh1 = *(const short8*)&Hsp[((4+q)*64 + mt*16 + l15)*8];
      f32x4 az = {0.f,0.f,0.f,0.f}, ar = {0.f,0.f,0.f,0.f};
      az = __builtin_amdgcn_mfma_f32_16x16x32_bf16(fa,  wz[0], az, 0,0,0);
      az = __builtin_amdgcn_mfma_f32_16x16x32_bf16(fh0, wz[1], az, 0,0,0);
      az = __builtin_amdgcn_mfma_f32_16x16x32_bf16(fh1, wz[2], az, 0,0,0);
      ar = __builtin_amdgcn_mfma_f32_16x16x32_bf16(fa,  wr[0], ar, 0,0,0);
      ar = __builtin_amdgcn_mfma_f32_16x16x32_bf16(fh0, wr[1], ar, 0,0,0);
      ar = __builtin_amdgcn_mfma_f32_16x16x32_bf16(fh1, wr[2], ar, 0,0,0);
      accZ[mt] = az; accR[mt] = ar;
    }
    // ---- activations: z kept in regs (C-layout), h*sigm(r) -> HRp ----
    #pragma unroll
    for (int mt = 0; mt < 4; mt++){
      #pragma unroll
      for (int e = 0; e < 4; e++){
        int node = mt*16 + q*4 + e;
        float z = 1.f/(1.f + __expf(-(accZ[mt][e] + cz)));
        float r = 1.f/(1.f + __expf(-(accR[mt][e] + cr)));
        float hold = ubf((ushort_t)Hsp[hidx + node*8]);
        HRp[hidx + node*8] = (short)f2b(hold * r);
        accZ[mt][e] = z;
      }
    }
    __syncthreads();                          // HRp ready
    // ---- GEMM2: [A|HR] @ Wh ----
    #pragma unroll
    for (int mt = 0; mt < 4; mt++){
      short8 fa  = *(const short8*)&As [((q)*64   + mt*16 + l15)*8];
      short8 fr0 = *(const short8*)&HRp[((q)*64   + mt*16 + l15)*8];
      short8 fr1 = *(const short8*)&HRp[((4+q)*64 + mt*16 + l15)*8];
      f32x4 ahh = {0.f,0.f,0.f,0.f};
      ahh = __builtin_amdgcn_mfma_f32_16x16x32_bf16(fa,  wh[0], ahh, 0,0,0);
      ahh = __builtin_amdgcn_mfma_f32_16x16x32_bf16(fr0, wh[1], ahh, 0,0,0);
      ahh = __builtin_amdgcn_mfma_f32_16x16x32_bf16(fr1, wh[2], ahh, 0,0,0);
      accR[mt] = ahh;                         // reuse as Ht_pre
    }
    float hn[4][4];
    #pragma unroll
    for (int mt = 0; mt < 4; mt++){
      #pragma unroll
      for (int e = 0; e < 4; e++){
        int node = mt*16 + q*4 + e;
        float xv = accR[mt][e] + ch;
        float ex = __expf(-2.f*fabsf(xv));
        float th = (1.f - ex)/(1.f + ex);
        th = (xv < 0.f) ? -th : th;
        float hold = ubf((ushort_t)Hsp[hidx + node*8]);
        float z = accZ[mt][e];
        hn[mt][e] = z*hold + (1.f - z)*th;
      }
    }
    __syncthreads();                          // all Hsp reads done
    #pragma unroll
    for (int mt = 0; mt < 4; mt++){
      #pragma unroll
      for (int e = 0; e < 4; e++){
        int node = mt*16 + q*4 + e;
        Hsp[hidx + node*8] = (short)f2b(hn[mt][e]);
      }
    }
  }
  __syncthreads();
  // ---- out projection: wave wv -> m-tile wv; K=64 over final h ----
  short8 wo0 = ((const short8*)wfrag)[36*64 + lane];
  short8 wo1 = ((const short8*)wfrag)[37*64 + lane];
  short8 f0 = *(const short8*)&Hsp[((q)*64   + wv*16 + l15)*8];
  short8 f1 = *(const short8*)&Hsp[((4+q)*64 + wv*16 + l15)*8];
  f32x4 ao = {0.f,0.f,0.f,0.f};
  ao = __builtin_amdgcn_mfma_f32_16x16x32_bf16(f0, wo0, ao, 0,0,0);
  ao = __builtin_amdgcn_mfma_f32_16x16x32_bf16(f1, wo1, ao, 0,0,0);
  float ob = w[OFF_OB + l15];
  #pragma unroll
  for (int e = 0; e < 4; e++){
    int gn = nb + wv*16 + q*4 + e;
    if (gn < NN) out[gn*OO + l15] = ao[e] + ob;
  }
}

extern "C" void kernel_launch(void* const* d_in, const int* in_sizes, int n_in,
                              void* d_out, int out_size, void* d_ws, size_t ws_size,
                              hipStream_t stream) {
  const float* xs = (const float*)d_in[0];
  const int*   ei = (const int*)d_in[1];
  float* out = (float*)d_out;
  char* ws = (char*)d_ws;
  // workspace layout (bytes); total ~58.6 MB
  ushort_t*  aggb   = (ushort_t*)(ws + 0);           // 19,200,000
  ushort_t*  xb     = (ushort_t*)(ws + 19200000);    // 19,200,000
  ushort_t*  ssrc16 = (ushort_t*)(ws + 38400000);    // 12,582,912
  uchar_t*   sdst8  = (uchar_t*) (ws + 50982912);    //  6,291,456
  float*     dinv   = (float*)   (ws + 57274368);    //  1,200,000
  int*       bcur   = (int*)     (ws + 58474368);    //  6,144
  float*     wbuf   = (float*)   (ws + 58480512);    //  78,656
  short*     wfrag  = (short*)   (ws + 58559168);    //  38,912 -> end 58,598,080

  zero_kernel<<<2, 256, 0, stream>>>((uint4*)(ws + 58474368), 384);   // bcur
  cvt_kernel<<<(2400000 + 255)/256, 256, 0, stream>>>((const float4*)xs, (ushort4*)xb, 2400000);
  prep_kernel<<<(WBUF_N + 255)/256, 256, 0, stream>>>(d_in[2],d_in[3],d_in[4],d_in[5],
      d_in[6],d_in[7],d_in[8],d_in[9],d_in[10],d_in[11],d_in[12],d_in[13],d_in[14],d_in[15],
      wbuf);
  prep2_kernel<<<(WFRAG_N + 255)/256, 256, 0, stream>>>(wbuf, wfrag);
  scatter_kernel<<<dim3((EE + CHUNK-1)/CHUNK, TT), 256, 0, stream>>>(ei, bcur, ssrc16, sdst8);
  degdinv_kernel<<<dim3(NB, TT), 256, 0, stream>>>(sdst8, bcur, dinv);
  gatherb_kernel<<<dim3(NB, TT), 256, 0, stream>>>(xb, dinv, ssrc16, sdst8, bcur, aggb);
  gates_kernel<<<(NN + 63)/64, 256, 0, stream>>>(aggb, wbuf, wfrag, out);
}

// Round 10
// 403.691 us; speedup vs baseline: 2.3531x; 1.0222x over previous
//
#include <hip/hip_runtime.h>
#include <hip/hip_bf16.h>

#define TT 6
#define NN 50000
#define EE 800000
#define FF 32
#define HH 64
#define OO 16

#define NB 256        // dst buckets
#define DPB 196       // dsts per bucket (256*196 = 50176 >= 50000)
#define CHUNK 4096    // edges per block in scatter
#define CAP 4096      // slab capacity per (t,bucket): mean 3125, sd 56 -> 17 sigma
#define SCAP 4096     // sorted-edge LDS capacity (== CAP)

// fused weight buffer layout (float offsets)
#define OFF_M 0        // M[g][32][64], g = z,r,h : W_g @ L_g[:64]
#define OFF_B 6144     // B[g][64][64]            : L_g[64:]
#define OFF_C 18432    // c[g][64]                : b_g @ L_g[:64] + L_g_b
#define OFF_OW 18624   // out_W [64][16]
#define OFF_OB 19648   // out_b [16]
#define WBUF_N 19664
#define WFRAG_N 19456  // 38 slots * 512 bf16 fragment-packed weights

typedef unsigned short ushort_t;
typedef unsigned char uchar_t;
typedef short short8 __attribute__((ext_vector_type(8)));   // 8 bf16 (4 VGPRs)
typedef float f32x4 __attribute__((ext_vector_type(4)));

__device__ __forceinline__ float ldf(const void* p, int i){ return ((const float*)p)[i]; }
__device__ __forceinline__ float ubf(ushort_t v){ return __uint_as_float(((unsigned)v) << 16); }
__device__ __forceinline__ ushort_t f2b(float f){
  unsigned u = __float_as_uint(f);
  return (ushort_t)((u + 0x7FFFu + ((u >> 16) & 1u)) >> 16);
}

// ---------------- zero ----------------
__global__ void zero_kernel(uint4* __restrict__ p, int n4){
  int i = blockIdx.x*256 + threadIdx.x;
  if (i < n4) p[i] = make_uint4(0,0,0,0);
}

// ---------------- f32 -> bf16 convert (xs -> xb) ----------------
__global__ void cvt_kernel(const float4* __restrict__ x, ushort4* __restrict__ xb, int n4){
  int i = blockIdx.x*256 + threadIdx.x;
  if (i < n4){
    float4 v = x[i];
    ushort4 o;
    o.x = f2b(v.x); o.y = f2b(v.y); o.z = f2b(v.z); o.w = f2b(v.w);
    xb[i] = o;
  }
}

// ---------------- fused-weight prep (all inputs f32) ----------------
__global__ void prep_kernel(const void* Wz,const void* bz,const void* Wr,const void* br,
                            const void* Wh,const void* bh,
                            const void* Lz,const void* Lzb,const void* Lr,const void* Lrb,
                            const void* Lh,const void* Lhb,
                            const void* oW,const void* ob, float* __restrict__ wbuf){
  int idx = blockIdx.x*256 + threadIdx.x;
  if (idx >= WBUF_N) return;
  if (idx < OFF_B){                       // M[g][k][j] = sum_m W[k][m] * L[m][j]
    int g = idx >> 11; int r = idx & 2047; int k = r >> 6; int j = r & 63;
    const void* W = (g==0)?Wz:((g==1)?Wr:Wh);
    const void* L = (g==0)?Lz:((g==1)?Lr:Lh);
    float s = 0.f;
    for (int m=0;m<64;m++) s += ldf(W,k*64+m) * ldf(L,m*64+j);
    wbuf[idx] = s;
  } else if (idx < OFF_C){                // B[g][k][j] = L[(64+k)][j]
    int i = idx - OFF_B; int g = i >> 12; int r = i & 4095; int k = r >> 6; int j = r & 63;
    const void* L = (g==0)?Lz:((g==1)?Lr:Lh);
    wbuf[idx] = ldf(L,(64+k)*64 + j);
  } else if (idx < OFF_OW){               // c[g][j] = sum_m b[m]*L[m][j] + Lb[j]
    int i = idx - OFF_C; int g = i >> 6; int j = i & 63;
    const void* L  = (g==0)?Lz:((g==1)?Lr:Lh);
    const void* bb = (g==0)?bz:((g==1)?br:bh);
    const void* Lb = (g==0)?Lzb:((g==1)?Lrb:Lhb);
    float s = ldf(Lb,j);
    for (int m=0;m<64;m++) s += ldf(bb,m) * ldf(L,m*64+j);
    wbuf[idx] = s;
  } else if (idx < OFF_OB){
    wbuf[idx] = ldf(oW,idx - OFF_OW);
  } else {
    wbuf[idx] = ldf(ob,idx - OFF_OB);
  }
}

// ---------------- weight fragment packing (B-operand layout, bf16) ----------------
__global__ void prep2_kernel(const float* __restrict__ wbuf, short* __restrict__ wfrag){
  int idx = blockIdx.x*256 + threadIdx.x;   // 0..19455
  if (idx >= WFRAG_N) return;
  int slot = idx >> 9;
  int lane = (idx >> 3) & 63;
  int j = idx & 7;
  int q = lane >> 4, l15 = lane & 15;
  float val;
  if (slot < 24){
    int nt = slot/3, kc = slot - nt*3;
    int ncol = nt*16 + l15;          // 0..127 (Z then R)
    int k = kc*32 + q*8 + j;         // 0..95
    int g = (ncol < 64) ? 0 : 1;
    int jin = ncol & 63;
    val = (k < 32) ? wbuf[OFF_M + g*2048 + k*64 + jin]
                   : wbuf[OFF_B + g*4096 + (k-32)*64 + jin];
  } else if (slot < 36){
    int s2 = slot - 24;
    int nt = s2/3, kc = s2 - nt*3;
    int ncol = nt*16 + l15;          // 0..63
    int k = kc*32 + q*8 + j;
    val = (k < 32) ? wbuf[OFF_M + 2*2048 + k*64 + ncol]
                   : wbuf[OFF_B + 2*4096 + (k-32)*64 + ncol];
  } else {
    int kc = slot - 36;
    int k = kc*32 + q*8 + j;         // 0..63
    val = wbuf[OFF_OW + k*16 + l15];
  }
  wfrag[idx] = (short)f2b(val);
}

// ---------------- scatter: LDS counting-sort by bucket -> coalesced slab writes --
__global__ __launch_bounds__(256) void scatter_kernel(const int* __restrict__ ei,
                                                      int* __restrict__ bcur,
                                                      ushort_t* __restrict__ ssrc16,
                                                      uchar_t* __restrict__ sdst8){
  int t = blockIdx.y;
  __shared__ int cnt[NB];
  __shared__ int lstart[NB];
  __shared__ int gbase[NB];
  __shared__ int wsum[4];
  __shared__ ushort_t spay[CHUNK];
  __shared__ uchar_t  sdlo[CHUNK];
  __shared__ uchar_t  sbk[CHUNK];
  int tid = threadIdx.x;
  cnt[tid] = 0;
  __syncthreads();
  int e0 = blockIdx.x*CHUNK;
  const int* srcs = ei + t*2*EE;
  const int* dsts = ei + t*2*EE + EE;
  int pk[CHUNK/256];
  int ps[CHUNK/256];
  int pd[CHUNK/256];
  #pragma unroll
  for (int i = 0; i < CHUNK/256; i++){
    int e = e0 + i*256 + tid;
    if (e < EE){
      int s = srcs[e], d = dsts[e];
      int b = d / DPB;
      int lr = atomicAdd(&cnt[b], 1);
      pk[i] = (b << 12) | lr;
      ps[i] = s;
      pd[i] = d - b*DPB;
    } else pk[i] = -1;
  }
  __syncthreads();
  {
    int v = cnt[tid];
    int lane = tid & 63, wid = tid >> 6;
    int x = v;
    #pragma unroll
    for (int o = 1; o < 64; o <<= 1){
      int y = __shfl_up(x, o, 64);
      if (lane >= o) x += y;
    }
    if (lane == 63) wsum[wid] = x;
    __syncthreads();
    if (tid == 0){
      int s = 0;
      #pragma unroll
      for (int w = 0; w < 4; w++){ int tmp = wsum[w]; wsum[w] = s; s += tmp; }
    }
    __syncthreads();
    lstart[tid] = x - v + wsum[wid];
    gbase[tid] = (v > 0) ? atomicAdd(&bcur[t*NB + tid], v) : 0;
  }
  __syncthreads();
  #pragma unroll
  for (int i = 0; i < CHUNK/256; i++){
    if (pk[i] >= 0){
      int b = pk[i] >> 12, lr = pk[i] & 4095;
      int pos = lstart[b] + lr;
      spay[pos] = (ushort_t)ps[i];
      sdlo[pos] = (uchar_t)pd[i];
      sbk[pos]  = (uchar_t)b;
    }
  }
  __syncthreads();
  int nE = EE - e0; if (nE > CHUNK) nE = CHUNK;
  for (int i = tid; i < nE; i += 256){
    int b = sbk[i];
    int gpos = gbase[b] + (i - lstart[b]);
    if (gpos < CAP){
      size_t sb = (size_t)(t*NB + b)*CAP + gpos;
      ssrc16[sb] = spay[i];
      sdst8[sb]  = sdlo[i];
    }
  }
}

// ---------------- per-bucket degree -> dinv (reads u8 slab only) ----------------
__global__ __launch_bounds__(256) void degdinv_kernel(const uchar_t* __restrict__ sdst8,
                                                      const int* __restrict__ bcur,
                                                      float* __restrict__ dinv){
  int b = blockIdx.x, t = blockIdx.y, tid = threadIdx.x;
  __shared__ int cnt[DPB];
  for (int i = tid; i < DPB; i += 256) cnt[i] = 0;
  __syncthreads();
  int ecnt = bcur[t*NB + b]; if (ecnt > CAP) ecnt = CAP;
  const uchar_t* dp = sdst8 + (size_t)(t*NB + b)*CAP;
  for (int i = tid; i < ecnt; i += 256)
    atomicAdd(&cnt[dp[i]], 1);
  __syncthreads();
  for (int i = tid; i < DPB; i += 256){
    int n = b*DPB + i;
    if (n < NN) dinv[t*NN + n] = rsqrtf((float)(cnt[i] + 1));  // +1 self loop
  }
}

// ---------------- bucket gather: counting-sort + register reduce ----------------
// XCD t-affinity swizzle: flat 1536-block grid, w = (bid&7)*192 + (bid>>3),
// t = w/256, b = w%256. Round-robin bid->XCD means each XCD's resident blocks
// span <=2 consecutive t's (6.4 MB xb) instead of all 6 (19.2 MB) -> L2 reuse.
__global__ __launch_bounds__(256) void gatherb_kernel(const ushort_t* __restrict__ xb,
                                                      const float* __restrict__ dinv,
                                                      const ushort_t* __restrict__ ssrc16,
                                                      const uchar_t* __restrict__ sdst8,
                                                      const int* __restrict__ bcur,
                                                      ushort_t* __restrict__ aggb){
  int l = blockIdx.x;
  int wk = ((l & 7) * 192) + (l >> 3);
  int t = wk >> 8;
  int b = wk & 255;
  int tid = threadIdx.x;
  __shared__ ushort_t ssrc[SCAP];
  __shared__ int cnt[DPB];
  __shared__ int off[DPB+1];
  __shared__ int wsum[4];
  for (int i = tid; i < DPB; i += 256) cnt[i] = 0;
  __syncthreads();
  int ecnt = bcur[t*NB + b]; if (ecnt > CAP) ecnt = CAP;
  size_t slab = (size_t)(t*NB + b)*CAP;
  const ushort_t* sp = ssrc16 + slab;
  const uchar_t*  dp = sdst8 + slab;
  unsigned pe[CAP/256]; int ne = 0;
  for (int e = tid; e < ecnt; e += 256){
    unsigned s = sp[e];
    unsigned dlo = dp[e];
    pe[ne++] = (dlo << 16) | s;
    atomicAdd(&cnt[dlo], 1);
  }
  __syncthreads();
  int v = (tid < DPB) ? cnt[tid] : 0;
  int lane = tid & 63, wid = tid >> 6;
  int x = v;
  #pragma unroll
  for (int o = 1; o < 64; o <<= 1){
    int y = __shfl_up(x, o, 64);
    if (lane >= o) x += y;
  }
  if (lane == 63) wsum[wid] = x;
  __syncthreads();
  if (tid == 0){
    int s = 0;
    #pragma unroll
    for (int w = 0; w < 4; w++){ int tmp = wsum[w]; wsum[w] = s; s += tmp; }
  }
  __syncthreads();
  int excl = x - v + wsum[wid];
  if (tid < DPB){ off[tid] = excl; cnt[tid] = excl; }
  if (tid == DPB-1) off[DPB] = excl + v;
  __syncthreads();
  for (int i = 0; i < ne; i++){
    unsigned p = pe[i];
    int r = atomicAdd(&cnt[p >> 16], 1);
    if (r < SCAP) ssrc[r] = (ushort_t)(p & 0xFFFFu);
  }
  __syncthreads();
  int w = tid >> 6;
  int eh = (tid >> 5) & 1;
  int f = tid & 31;
  const ushort_t* xbt = xb + (size_t)t*NN*FF;
  const float* dv = dinv + t*NN;
  for (int d = w*49; d < w*49 + 49; d++){
    int e0 = off[d], e1 = off[d+1];
    float accf = 0.f;
    int i = e0 + eh;
    int scur = (i < e1) ? (int)ssrc[i] : 0;
    while (i < e1){
      int inext = i + 2;
      int snxt = (inext < e1) ? (int)ssrc[inext] : 0;
      float dvs = dv[scur];
      float xv = ubf(xbt[(size_t)scur*FF + f]);
      accf += dvs * xv;
      i = inext; scur = snxt;
    }
    float sum = accf + __shfl_xor(accf, 32, 64);
    int n = b*DPB + d;
    if (eh == 0 && n < NN){
      float dn = dv[n];
      float sv = ubf(xbt[(size_t)n*FF + f]);
      aggb[((size_t)t*NN + n)*FF + f] = f2b(dn*(sum + dn*sv));
    }
  }
}

// ---------------- ALL GRU steps, MFMA version; h LDS-resident; out fused --------
__global__ __launch_bounds__(256) void gates_kernel(const ushort_t* __restrict__ aggb,
                                                    const float* __restrict__ w,
                                                    const short* __restrict__ wfrag,
                                                    float* __restrict__ out){
  __shared__ __align__(16) short As[2048];    // 64 x 32  (4 KB)
  __shared__ __align__(16) short Hsp[4096];   // 64 x 64  (8 KB)
  __shared__ __align__(16) short HRp[4096];   // 64 x 64  (8 KB)
  int tid = threadIdx.x;
  int nb = blockIdx.x*64;
  int wv = tid >> 6, lane = tid & 63;
  int q = lane >> 4, l15 = lane & 15;
  #pragma unroll
  for (int r = 0; r < 8; r++) ((int*)Hsp)[tid + 256*r] = 0;
  short8 wz[3], wr[3], wh[3];
  #pragma unroll
  for (int kc = 0; kc < 3; kc++){
    wz[kc] = ((const short8*)wfrag)[(wv*3 + kc)*64 + lane];
    wr[kc] = ((const short8*)wfrag)[((wv+4)*3 + kc)*64 + lane];
    wh[kc] = ((const short8*)wfrag)[(24 + wv*3 + kc)*64 + lane];
  }
  int jz = wv*16 + l15;
  float cz = w[OFF_C + jz], cr = w[OFF_C + 64 + jz], ch = w[OFF_C + 128 + jz];
  int hidx = ((jz >> 3)*64)*8 + (jz & 7);
  f32x4 accZ[4], accR[4];
  for (int t = 0; t < TT; t++){
    {
      int n = tid >> 2, c = tid & 3, gn = nb + n;
      uint4 v = make_uint4(0,0,0,0);
      if (gn < NN) v = ((const uint4*)aggb)[((size_t)t*NN + gn)*4 + (size_t)c];
      *(uint4*)&As[(c*64 + n)*8] = v;
    }
    __syncthreads();
    #pragma unroll
    for (int mt = 0; mt < 4; mt++){
      short8 fa  = *(const short8*)&As [((q)*64   + mt*16 + l15)*8];
      short8 fh0 = *(const short8*)&Hsp[((q)*64   + mt*16 + l15)*8];
      short8 fh1 = *(const short8*)&Hsp[((4+q)*64 + mt*16 + l15)*8];
      f32x4 az = {0.f,0.f,0.f,0.f}, ar = {0.f,0.f,0.f,0.f};
      az = __builtin_amdgcn_mfma_f32_16x16x32_bf16(fa,  wz[0], az, 0,0,0);
      az = __builtin_amdgcn_mfma_f32_16x16x32_bf16(fh0, wz[1], az, 0,0,0);
      az = __builtin_amdgcn_mfma_f32_16x16x32_bf16(fh1, wz[2], az, 0,0,0);
      ar = __builtin_amdgcn_mfma_f32_16x16x32_bf16(fa,  wr[0], ar, 0,0,0);
      ar = __builtin_amdgcn_mfma_f32_16x16x32_bf16(fh0, wr[1], ar, 0,0,0);
      ar = __builtin_amdgcn_mfma_f32_16x16x32_bf16(fh1, wr[2], ar, 0,0,0);
      accZ[mt] = az; accR[mt] = ar;
    }
    #pragma unroll
    for (int mt = 0; mt < 4; mt++){
      #pragma unroll
      for (int e = 0; e < 4; e++){
        int node = mt*16 + q*4 + e;
        float z = 1.f/(1.f + __expf(-(accZ[mt][e] + cz)));
        float r = 1.f/(1.f + __expf(-(accR[mt][e] + cr)));
        float hold = ubf((ushort_t)Hsp[hidx + node*8]);
        HRp[hidx + node*8] = (short)f2b(hold * r);
        accZ[mt][e] = z;
      }
    }
    __syncthreads();
    #pragma unroll
    for (int mt = 0; mt < 4; mt++){
      short8 fa  = *(const short8*)&As [((q)*64   + mt*16 + l15)*8];
      short8 fr0 = *(const short8*)&HRp[((q)*64   + mt*16 + l15)*8];
      short8 fr1 = *(const short8*)&HRp[((4+q)*64 + mt*16 + l15)*8];
      f32x4 ahh = {0.f,0.f,0.f,0.f};
      ahh = __builtin_amdgcn_mfma_f32_16x16x32_bf16(fa,  wh[0], ahh, 0,0,0);
      ahh = __builtin_amdgcn_mfma_f32_16x16x32_bf16(fr0, wh[1], ahh, 0,0,0);
      ahh = __builtin_amdgcn_mfma_f32_16x16x32_bf16(fr1, wh[2], ahh, 0,0,0);
      accR[mt] = ahh;
    }
    float hn[4][4];
    #pragma unroll
    for (int mt = 0; mt < 4; mt++){
      #pragma unroll
      for (int e = 0; e < 4; e++){
        int node = mt*16 + q*4 + e;
        float xv = accR[mt][e] + ch;
        float ex = __expf(-2.f*fabsf(xv));
        float th = (1.f - ex)/(1.f + ex);
        th = (xv < 0.f) ? -th : th;
        float hold = ubf((ushort_t)Hsp[hidx + node*8]);
        float z = accZ[mt][e];
        hn[mt][e] = z*hold + (1.f - z)*th;
      }
    }
    __syncthreads();
    #pragma unroll
    for (int mt = 0; mt < 4; mt++){
      #pragma unroll
      for (int e = 0; e < 4; e++){
        int node = mt*16 + q*4 + e;
        Hsp[hidx + node*8] = (short)f2b(hn[mt][e]);
      }
    }
  }
  __syncthreads();
  short8 wo0 = ((const short8*)wfrag)[36*64 + lane];
  short8 wo1 = ((const short8*)wfrag)[37*64 + lane];
  short8 f0 = *(const short8*)&Hsp[((q)*64   + wv*16 + l15)*8];
  short8 f1 = *(const short8*)&Hsp[((4+q)*64 + wv*16 + l15)*8];
  f32x4 ao = {0.f,0.f,0.f,0.f};
  ao = __builtin_amdgcn_mfma_f32_16x16x32_bf16(f0, wo0, ao, 0,0,0);
  ao = __builtin_amdgcn_mfma_f32_16x16x32_bf16(f1, wo1, ao, 0,0,0);
  float ob = w[OFF_OB + l15];
  #pragma unroll
  for (int e = 0; e < 4; e++){
    int gn = nb + wv*16 + q*4 + e;
    if (gn < NN) out[gn*OO + l15] = ao[e] + ob;
  }
}

extern "C" void kernel_launch(void* const* d_in, const int* in_sizes, int n_in,
                              void* d_out, int out_size, void* d_ws, size_t ws_size,
                              hipStream_t stream) {
  const float* xs = (const float*)d_in[0];
  const int*   ei = (const int*)d_in[1];
  float* out = (float*)d_out;
  char* ws = (char*)d_ws;
  // workspace layout (bytes); total ~58.6 MB
  ushort_t*  aggb   = (ushort_t*)(ws + 0);           // 19,200,000
  ushort_t*  xb     = (ushort_t*)(ws + 19200000);    // 19,200,000
  ushort_t*  ssrc16 = (ushort_t*)(ws + 38400000);    // 12,582,912
  uchar_t*   sdst8  = (uchar_t*) (ws + 50982912);    //  6,291,456
  float*     dinv   = (float*)   (ws + 57274368);    //  1,200,000
  int*       bcur   = (int*)     (ws + 58474368);    //  6,144
  float*     wbuf   = (float*)   (ws + 58480512);    //  78,656
  short*     wfrag  = (short*)   (ws + 58559168);    //  38,912 -> end 58,598,080

  zero_kernel<<<2, 256, 0, stream>>>((uint4*)(ws + 58474368), 384);   // bcur
  cvt_kernel<<<(2400000 + 255)/256, 256, 0, stream>>>((const float4*)xs, (ushort4*)xb, 2400000);
  prep_kernel<<<(WBUF_N + 255)/256, 256, 0, stream>>>(d_in[2],d_in[3],d_in[4],d_in[5],
      d_in[6],d_in[7],d_in[8],d_in[9],d_in[10],d_in[11],d_in[12],d_in[13],d_in[14],d_in[15],
      wbuf);
  prep2_kernel<<<(WFRAG_N + 255)/256, 256, 0, stream>>>(wbuf, wfrag);
  scatter_kernel<<<dim3((EE + CHUNK-1)/CHUNK, TT), 256, 0, stream>>>(ei, bcur, ssrc16, sdst8);
  degdinv_kernel<<<dim3(NB, TT), 256, 0, stream>>>(sdst8, bcur, dinv);
  gatherb_kernel<<<NB*TT, 256, 0, stream>>>(xb, dinv, ssrc16, sdst8, bcur, aggb);
  gates_kernel<<<(NN + 63)/64, 256, 0, stream>>>(aggb, wbuf, wfrag, out);
}

// Round 11
// 338.415 us; speedup vs baseline: 2.8070x; 1.1929x over previous
//
#include <hip/hip_runtime.h>
#include <hip/hip_bf16.h>

#define TT 6
#define NN 50000
#define EE 800000
#define FF 32
#define HH 64
#define OO 16

#define NB 256        // dst buckets
#define DPB 196       // dsts per bucket (256*196 = 50176 >= 50000)
#define CHUNK 4096    // edges per block in scatter
#define CAP 4096      // slab capacity per (t,bucket): mean 3125, sd 56 -> 17 sigma
#define HDPB 98       // dsts per gather sub-block
#define HCAP 2560     // sorted-edge LDS capacity per half (mean 1562, +25 sigma)

// fused weight buffer layout (float offsets)
#define OFF_M 0        // M[g][32][64], g = z,r,h : W_g @ L_g[:64]
#define OFF_B 6144     // B[g][64][64]            : L_g[64:]
#define OFF_C 18432    // c[g][64]                : b_g @ L_g[:64] + L_g_b
#define OFF_OW 18624   // out_W [64][16]
#define OFF_OB 19648   // out_b [16]
#define WBUF_N 19664
#define WFRAG_N 19456  // 38 slots * 512 bf16 fragment-packed weights

typedef unsigned short ushort_t;
typedef unsigned char uchar_t;
typedef short short8 __attribute__((ext_vector_type(8)));   // 8 bf16 (4 VGPRs)
typedef float f32x4 __attribute__((ext_vector_type(4)));

__device__ __forceinline__ float ldf(const void* p, int i){ return ((const float*)p)[i]; }
__device__ __forceinline__ float ubf(ushort_t v){ return __uint_as_float(((unsigned)v) << 16); }
__device__ __forceinline__ ushort_t f2b(float f){
  unsigned u = __float_as_uint(f);
  return (ushort_t)((u + 0x7FFFu + ((u >> 16) & 1u)) >> 16);
}
__device__ __forceinline__ float lo16f(unsigned u){ return __uint_as_float(u << 16); }
__device__ __forceinline__ float hi16f(unsigned u){ return __uint_as_float(u & 0xFFFF0000u); }

// ---------------- zero ----------------
__global__ void zero_kernel(uint4* __restrict__ p, int n4){
  int i = blockIdx.x*256 + threadIdx.x;
  if (i < n4) p[i] = make_uint4(0,0,0,0);
}

// ---------------- f32 -> bf16 convert (xs -> xb) ----------------
__global__ void cvt_kernel(const float4* __restrict__ x, ushort4* __restrict__ xb, int n4){
  int i = blockIdx.x*256 + threadIdx.x;
  if (i < n4){
    float4 v = x[i];
    ushort4 o;
    o.x = f2b(v.x); o.y = f2b(v.y); o.z = f2b(v.z); o.w = f2b(v.w);
    xb[i] = o;
  }
}

// ---------------- fused-weight prep (all inputs f32) ----------------
__global__ void prep_kernel(const void* Wz,const void* bz,const void* Wr,const void* br,
                            const void* Wh,const void* bh,
                            const void* Lz,const void* Lzb,const void* Lr,const void* Lrb,
                            const void* Lh,const void* Lhb,
                            const void* oW,const void* ob, float* __restrict__ wbuf){
  int idx = blockIdx.x*256 + threadIdx.x;
  if (idx >= WBUF_N) return;
  if (idx < OFF_B){                       // M[g][k][j] = sum_m W[k][m] * L[m][j]
    int g = idx >> 11; int r = idx & 2047; int k = r >> 6; int j = r & 63;
    const void* W = (g==0)?Wz:((g==1)?Wr:Wh);
    const void* L = (g==0)?Lz:((g==1)?Lr:Lh);
    float s = 0.f;
    for (int m=0;m<64;m++) s += ldf(W,k*64+m) * ldf(L,m*64+j);
    wbuf[idx] = s;
  } else if (idx < OFF_C){                // B[g][k][j] = L[(64+k)][j]
    int i = idx - OFF_B; int g = i >> 12; int r = i & 4095; int k = r >> 6; int j = r & 63;
    const void* L = (g==0)?Lz:((g==1)?Lr:Lh);
    wbuf[idx] = ldf(L,(64+k)*64 + j);
  } else if (idx < OFF_OW){               // c[g][j] = sum_m b[m]*L[m][j] + Lb[j]
    int i = idx - OFF_C; int g = i >> 6; int j = i & 63;
    const void* L  = (g==0)?Lz:((g==1)?Lr:Lh);
    const void* bb = (g==0)?bz:((g==1)?br:bh);
    const void* Lb = (g==0)?Lzb:((g==1)?Lrb:Lhb);
    float s = ldf(Lb,j);
    for (int m=0;m<64;m++) s += ldf(bb,m) * ldf(L,m*64+j);
    wbuf[idx] = s;
  } else if (idx < OFF_OB){
    wbuf[idx] = ldf(oW,idx - OFF_OW);
  } else {
    wbuf[idx] = ldf(ob,idx - OFF_OB);
  }
}

// ---------------- weight fragment packing (B-operand layout, bf16) ----------------
__global__ void prep2_kernel(const float* __restrict__ wbuf, short* __restrict__ wfrag){
  int idx = blockIdx.x*256 + threadIdx.x;   // 0..19455
  if (idx >= WFRAG_N) return;
  int slot = idx >> 9;
  int lane = (idx >> 3) & 63;
  int j = idx & 7;
  int q = lane >> 4, l15 = lane & 15;
  float val;
  if (slot < 24){
    int nt = slot/3, kc = slot - nt*3;
    int ncol = nt*16 + l15;          // 0..127 (Z then R)
    int k = kc*32 + q*8 + j;         // 0..95
    int g = (ncol < 64) ? 0 : 1;
    int jin = ncol & 63;
    val = (k < 32) ? wbuf[OFF_M + g*2048 + k*64 + jin]
                   : wbuf[OFF_B + g*4096 + (k-32)*64 + jin];
  } else if (slot < 36){
    int s2 = slot - 24;
    int nt = s2/3, kc = s2 - nt*3;
    int ncol = nt*16 + l15;          // 0..63
    int k = kc*32 + q*8 + j;
    val = (k < 32) ? wbuf[OFF_M + 2*2048 + k*64 + ncol]
                   : wbuf[OFF_B + 2*4096 + (k-32)*64 + ncol];
  } else {
    int kc = slot - 36;
    int k = kc*32 + q*8 + j;         // 0..63
    val = wbuf[OFF_OW + k*16 + l15];
  }
  wfrag[idx] = (short)f2b(val);
}

// ---------------- scatter: LDS counting-sort by bucket -> coalesced slab writes --
__global__ __launch_bounds__(256) void scatter_kernel(const int* __restrict__ ei,
                                                      int* __restrict__ bcur,
                                                      ushort_t* __restrict__ ssrc16,
                                                      uchar_t* __restrict__ sdst8){
  int t = blockIdx.y;
  __shared__ int cnt[NB];
  __shared__ int lstart[NB];
  __shared__ int gbase[NB];
  __shared__ int wsum[4];
  __shared__ ushort_t spay[CHUNK];
  __shared__ uchar_t  sdlo[CHUNK];
  __shared__ uchar_t  sbk[CHUNK];
  int tid = threadIdx.x;
  cnt[tid] = 0;
  __syncthreads();
  int e0 = blockIdx.x*CHUNK;
  const int* srcs = ei + t*2*EE;
  const int* dsts = ei + t*2*EE + EE;
  int pk[CHUNK/256];
  int ps[CHUNK/256];
  int pd[CHUNK/256];
  #pragma unroll
  for (int i = 0; i < CHUNK/256; i++){
    int e = e0 + i*256 + tid;
    if (e < EE){
      int s = srcs[e], d = dsts[e];
      int b = d / DPB;
      int lr = atomicAdd(&cnt[b], 1);
      pk[i] = (b << 12) | lr;
      ps[i] = s;
      pd[i] = d - b*DPB;
    } else pk[i] = -1;
  }
  __syncthreads();
  {
    int v = cnt[tid];
    int lane = tid & 63, wid = tid >> 6;
    int x = v;
    #pragma unroll
    for (int o = 1; o < 64; o <<= 1){
      int y = __shfl_up(x, o, 64);
      if (lane >= o) x += y;
    }
    if (lane == 63) wsum[wid] = x;
    __syncthreads();
    if (tid == 0){
      int s = 0;
      #pragma unroll
      for (int w = 0; w < 4; w++){ int tmp = wsum[w]; wsum[w] = s; s += tmp; }
    }
    __syncthreads();
    lstart[tid] = x - v + wsum[wid];
    gbase[tid] = (v > 0) ? atomicAdd(&bcur[t*NB + tid], v) : 0;
  }
  __syncthreads();
  #pragma unroll
  for (int i = 0; i < CHUNK/256; i++){
    if (pk[i] >= 0){
      int b = pk[i] >> 12, lr = pk[i] & 4095;
      int pos = lstart[b] + lr;
      spay[pos] = (ushort_t)ps[i];
      sdlo[pos] = (uchar_t)pd[i];
      sbk[pos]  = (uchar_t)b;
    }
  }
  __syncthreads();
  int nE = EE - e0; if (nE > CHUNK) nE = CHUNK;
  for (int i = tid; i < nE; i += 256){
    int b = sbk[i];
    int gpos = gbase[b] + (i - lstart[b]);
    if (gpos < CAP){
      size_t sb = (size_t)(t*NB + b)*CAP + gpos;
      ssrc16[sb] = spay[i];
      sdst8[sb]  = sdlo[i];
    }
  }
}

// ---------------- per-bucket degree -> dinv (reads u8 slab only) ----------------
__global__ __launch_bounds__(256) void degdinv_kernel(const uchar_t* __restrict__ sdst8,
                                                      const int* __restrict__ bcur,
                                                      float* __restrict__ dinv){
  int b = blockIdx.x, t = blockIdx.y, tid = threadIdx.x;
  __shared__ int cnt[DPB];
  for (int i = tid; i < DPB; i += 256) cnt[i] = 0;
  __syncthreads();
  int ecnt = bcur[t*NB + b]; if (ecnt > CAP) ecnt = CAP;
  const uchar_t* dp = sdst8 + (size_t)(t*NB + b)*CAP;
  for (int i = tid; i < ecnt; i += 256)
    atomicAdd(&cnt[dp[i]], 1);
  __syncthreads();
  for (int i = tid; i < DPB; i += 256){
    int n = b*DPB + i;
    if (n < NN) dinv[t*NN + n] = rsqrtf((float)(cnt[i] + 1));  // +1 self loop
  }
}

// ---------------- bucket gather v3: half-bucket blocks, 4 edges/wave-iter, -------
// data-prefetched pipeline, uint (2-feature) loads/stores.
// Grid 3072; XCD t-affinity: w=(bid&7)*384+(bid>>3); t=w>>9; b=(w&511)>>1; sb=w&1.
__global__ __launch_bounds__(256) void gatherb_kernel(const ushort_t* __restrict__ xb,
                                                      const float* __restrict__ dinv,
                                                      const ushort_t* __restrict__ ssrc16,
                                                      const uchar_t* __restrict__ sdst8,
                                                      const int* __restrict__ bcur,
                                                      ushort_t* __restrict__ aggb){
  int l = blockIdx.x;
  int wk = ((l & 7) * 384) + (l >> 3);
  int t = wk >> 9;
  int r9 = wk & 511;
  int b = r9 >> 1;
  int sb = r9 & 1;
  int DLO0 = sb * HDPB;                 // my dst half [DLO0, DLO0+98)
  int tid = threadIdx.x;
  __shared__ ushort_t ssrc[HCAP];       // 5 KB srcs sorted by local dlo
  __shared__ int cnt[HDPB+2];
  __shared__ int off[HDPB+2];
  for (int i = tid; i < HDPB+2; i += 256) cnt[i] = 0;
  __syncthreads();
  int ecnt = bcur[t*NB + b]; if (ecnt > CAP) ecnt = CAP;
  size_t slab = (size_t)(t*NB + b)*CAP;
  const ushort_t* sp = ssrc16 + slab;
  const uchar_t*  dp = sdst8 + slab;
  unsigned pe[CAP/256]; int ne = 0;     // (ldlo<<16)|src for my half, in VGPRs
  for (int e = tid; e < ecnt; e += 256){
    unsigned s = sp[e];
    unsigned ld = (unsigned)dp[e] - (unsigned)DLO0;
    if (ld < (unsigned)HDPB){
      pe[ne++] = (ld << 16) | s;
      atomicAdd(&cnt[ld], 1);
    }
  }
  __syncthreads();
  if (tid == 0){                        // serial exclusive scan over 98 entries
    int s = 0;
    for (int i = 0; i < HDPB; i++){
      int c = cnt[i];
      off[i] = s; cnt[i] = s;           // cnt becomes rank cursor
      s += c;
    }
    off[HDPB] = s;
  }
  __syncthreads();
  for (int k = 0; k < ne; k++){
    unsigned p = pe[k];
    int rr = atomicAdd(&cnt[p >> 16], 1);
    if (rr < HCAP) ssrc[rr] = (ushort_t)(p & 0xFFFFu);
  }
  __syncthreads();
  // reduce: wave wv owns ~25 dsts; 64 lanes = 4 edges x 16 feature-pairs
  int wv = tid >> 6, lane = tid & 63;
  int eg = lane >> 4;                   // edge group 0..3
  int fp = lane & 15;                   // feature pair (2 bf16 = uint)
  const unsigned* xb32 = (const unsigned*)xb + (size_t)t*NN*16;
  const unsigned* agg32base = (const unsigned*)aggb;
  const float* dv = dinv + t*NN;
  int d0  = (wv < 2) ? wv*25 : 50 + (wv-2)*24;
  int ndw = (wv < 2) ? 25 : 24;
  for (int dd = 0; dd < ndw; dd++){
    int ld = d0 + dd;
    int e0 = off[ld], e1 = off[ld+1];
    float ax = 0.f, ay = 0.f;
    int base = e0;
    int i0 = e0 + eg;
    bool v = (i0 < e1);
    int s0 = (int)ssrc[v ? i0 : 0];
    float dvc = dv[s0]; if (!v) dvc = 0.f;     // loads unconditional, mask scalar
    unsigned rvc = xb32[s0*16 + fp];
    while (base < e1){
      int nbase = base + 4;
      int inx = nbase + eg;
      bool vn = (inx < e1);
      int sn = (int)ssrc[vn ? inx : 0];
      float dvn = dv[sn];                      // prefetch next (in flight during fma)
      unsigned rvn = xb32[sn*16 + fp];
      ax += dvc * lo16f(rvc);
      ay += dvc * hi16f(rvc);
      dvc = vn ? dvn : 0.f;
      rvc = rvn;
      base = nbase;
    }
    float sx = ax + __shfl_xor(ax, 16, 64); sx += __shfl_xor(sx, 32, 64);
    float sy = ay + __shfl_xor(ay, 16, 64); sy += __shfl_xor(sy, 32, 64);
    int n = b*DPB + DLO0 + ld;
    if (eg == 0 && n < NN){
      float dn = dv[n];
      unsigned sv = xb32[n*16 + fp];           // self term
      float ox = dn*(sx + dn*lo16f(sv));
      float oy = dn*(sy + dn*hi16f(sv));
      unsigned pk = (unsigned)f2b(ox) | ((unsigned)f2b(oy) << 16);
      ((unsigned*)agg32base)[(size_t)(t*NN + n)*16 + fp] = pk;
    }
  }
}

// ---------------- ALL GRU steps, MFMA version; h LDS-resident; out fused --------
__global__ __launch_bounds__(256) void gates_kernel(const ushort_t* __restrict__ aggb,
                                                    const float* __restrict__ w,
                                                    const short* __restrict__ wfrag,
                                                    float* __restrict__ out){
  __shared__ __align__(16) short As[2048];    // 64 x 32  (4 KB)
  __shared__ __align__(16) short Hsp[4096];   // 64 x 64  (8 KB)
  __shared__ __align__(16) short HRp[4096];   // 64 x 64  (8 KB)
  int tid = threadIdx.x;
  int nb = blockIdx.x*64;
  int wv = tid >> 6, lane = tid & 63;
  int q = lane >> 4, l15 = lane & 15;
  #pragma unroll
  for (int r = 0; r < 8; r++) ((int*)Hsp)[tid + 256*r] = 0;
  short8 wz[3], wr[3], wh[3];
  #pragma unroll
  for (int kc = 0; kc < 3; kc++){
    wz[kc] = ((const short8*)wfrag)[(wv*3 + kc)*64 + lane];
    wr[kc] = ((const short8*)wfrag)[((wv+4)*3 + kc)*64 + lane];
    wh[kc] = ((const short8*)wfrag)[(24 + wv*3 + kc)*64 + lane];
  }
  int jz = wv*16 + l15;
  float cz = w[OFF_C + jz], cr = w[OFF_C + 64 + jz], ch = w[OFF_C + 128 + jz];
  int hidx = ((jz >> 3)*64)*8 + (jz & 7);
  f32x4 accZ[4], accR[4];
  for (int t = 0; t < TT; t++){
    {
      int n = tid >> 2, c = tid & 3, gn = nb + n;
      uint4 v = make_uint4(0,0,0,0);
      if (gn < NN) v = ((const uint4*)aggb)[((size_t)t*NN + gn)*4 + (size_t)c];
      *(uint4*)&As[(c*64 + n)*8] = v;
    }
    __syncthreads();
    #pragma unroll
    for (int mt = 0; mt < 4; mt++){
      short8 fa  = *(const short8*)&As [((q)*64   + mt*16 + l15)*8];
      short8 fh0 = *(const short8*)&Hsp[((q)*64   + mt*16 + l15)*8];
      short8 fh1 = *(const short8*)&Hsp[((4+q)*64 + mt*16 + l15)*8];
      f32x4 az = {0.f,0.f,0.f,0.f}, ar = {0.f,0.f,0.f,0.f};
      az = __builtin_amdgcn_mfma_f32_16x16x32_bf16(fa,  wz[0], az, 0,0,0);
      az = __builtin_amdgcn_mfma_f32_16x16x32_bf16(fh0, wz[1], az, 0,0,0);
      az = __builtin_amdgcn_mfma_f32_16x16x32_bf16(fh1, wz[2], az, 0,0,0);
      ar = __builtin_amdgcn_mfma_f32_16x16x32_bf16(fa,  wr[0], ar, 0,0,0);
      ar = __builtin_amdgcn_mfma_f32_16x16x32_bf16(fh0, wr[1], ar, 0,0,0);
      ar = __builtin_amdgcn_mfma_f32_16x16x32_bf16(fh1, wr[2], ar, 0,0,0);
      accZ[mt] = az; accR[mt] = ar;
    }
    #pragma unroll
    for (int mt = 0; mt < 4; mt++){
      #pragma unroll
      for (int e = 0; e < 4; e++){
        int node = mt*16 + q*4 + e;
        float z = 1.f/(1.f + __expf(-(accZ[mt][e] + cz)));
        float r = 1.f/(1.f + __expf(-(accR[mt][e] + cr)));
        float hold = ubf((ushort_t)Hsp[hidx + node*8]);
        HRp[hidx + node*8] = (short)f2b(hold * r);
        accZ[mt][e] = z;
      }
    }
    __syncthreads();
    #pragma unroll
    for (int mt = 0; mt < 4; mt++){
      short8 fa  = *(const short8*)&As [((q)*64   + mt*16 + l15)*8];
      short8 fr0 = *(const short8*)&HRp[((q)*64   + mt*16 + l15)*8];
      short8 fr1 = *(const short8*)&HRp[((4+q)*64 + mt*16 + l15)*8];
      f32x4 ahh = {0.f,0.f,0.f,0.f};
      ahh = __builtin_amdgcn_mfma_f32_16x16x32_bf16(fa,  wh[0], ahh, 0,0,0);
      ahh = __builtin_amdgcn_mfma_f32_16x16x32_bf16(fr0, wh[1], ahh, 0,0,0);
      ahh = __builtin_amdgcn_mfma_f32_16x16x32_bf16(fr1, wh[2], ahh, 0,0,0);
      accR[mt] = ahh;
    }
    float hn[4][4];
    #pragma unroll
    for (int mt = 0; mt < 4; mt++){
      #pragma unroll
      for (int e = 0; e < 4; e++){
        int node = mt*16 + q*4 + e;
        float xv = accR[mt][e] + ch;
        float ex = __expf(-2.f*fabsf(xv));
        float th = (1.f - ex)/(1.f + ex);
        th = (xv < 0.f) ? -th : th;
        float hold = ubf((ushort_t)Hsp[hidx + node*8]);
        float z = accZ[mt][e];
        hn[mt][e] = z*hold + (1.f - z)*th;
      }
    }
    __syncthreads();
    #pragma unroll
    for (int mt = 0; mt < 4; mt++){
      #pragma unroll
      for (int e = 0; e < 4; e++){
        int node = mt*16 + q*4 + e;
        Hsp[hidx + node*8] = (short)f2b(hn[mt][e]);
      }
    }
  }
  __syncthreads();
  short8 wo0 = ((const short8*)wfrag)[36*64 + lane];
  short8 wo1 = ((const short8*)wfrag)[37*64 + lane];
  short8 f0 = *(const short8*)&Hsp[((q)*64   + wv*16 + l15)*8];
  short8 f1 = *(const short8*)&Hsp[((4+q)*64 + wv*16 + l15)*8];
  f32x4 ao = {0.f,0.f,0.f,0.f};
  ao = __builtin_amdgcn_mfma_f32_16x16x32_bf16(f0, wo0, ao, 0,0,0);
  ao = __builtin_amdgcn_mfma_f32_16x16x32_bf16(f1, wo1, ao, 0,0,0);
  float ob = w[OFF_OB + l15];
  #pragma unroll
  for (int e = 0; e < 4; e++){
    int gn = nb + wv*16 + q*4 + e;
    if (gn < NN) out[gn*OO + l15] = ao[e] + ob;
  }
}

extern "C" void kernel_launch(void* const* d_in, const int* in_sizes, int n_in,
                              void* d_out, int out_size, void* d_ws, size_t ws_size,
                              hipStream_t stream) {
  const float* xs = (const float*)d_in[0];
  const int*   ei = (const int*)d_in[1];
  float* out = (float*)d_out;
  char* ws = (char*)d_ws;
  // workspace layout (bytes); total ~58.6 MB
  ushort_t*  aggb   = (ushort_t*)(ws + 0);           // 19,200,000
  ushort_t*  xb     = (ushort_t*)(ws + 19200000);    // 19,200,000
  ushort_t*  ssrc16 = (ushort_t*)(ws + 38400000);    // 12,582,912
  uchar_t*   sdst8  = (uchar_t*) (ws + 50982912);    //  6,291,456
  float*     dinv   = (float*)   (ws + 57274368);    //  1,200,000
  int*       bcur   = (int*)     (ws + 58474368);    //  6,144
  float*     wbuf   = (float*)   (ws + 58480512);    //  78,656
  short*     wfrag  = (short*)   (ws + 58559168);    //  38,912 -> end 58,598,080

  zero_kernel<<<2, 256, 0, stream>>>((uint4*)(ws + 58474368), 384);   // bcur
  cvt_kernel<<<(2400000 + 255)/256, 256, 0, stream>>>((const float4*)xs, (ushort4*)xb, 2400000);
  prep_kernel<<<(WBUF_N + 255)/256, 256, 0, stream>>>(d_in[2],d_in[3],d_in[4],d_in[5],
      d_in[6],d_in[7],d_in[8],d_in[9],d_in[10],d_in[11],d_in[12],d_in[13],d_in[14],d_in[15],
      wbuf);
  prep2_kernel<<<(WFRAG_N + 255)/256, 256, 0, stream>>>(wbuf, wfrag);
  scatter_kernel<<<dim3((EE + CHUNK-1)/CHUNK, TT), 256, 0, stream>>>(ei, bcur, ssrc16, sdst8);
  degdinv_kernel<<<dim3(NB, TT), 256, 0, stream>>>(sdst8, bcur, dinv);
  gatherb_kernel<<<NB*TT*2, 256, 0, stream>>>(xb, dinv, ssrc16, sdst8, bcur, aggb);
  gates_kernel<<<(NN + 63)/64, 256, 0, stream>>>(aggb, wbuf, wfrag, out);
}

// Round 12
// 302.048 us; speedup vs baseline: 3.1449x; 1.1204x over previous
//
#include <hip/hip_runtime.h>
#include <hip/hip_bf16.h>

#define TT 6
#define NN 50000
#define EE 800000
#define FF 32
#define HH 64
#define OO 16

#define NB 256        // dst buckets
#define DPB 196       // dsts per bucket (256*196 = 50176 >= 50000)
#define CHUNK 4096    // edges per block in scatter
#define CAP 4096      // slab capacity per (t,bucket): mean 3125, sd 56 -> 17 sigma
#define HDPB 98       // dsts per gather sub-block
#define HCAP 2560     // sorted-edge LDS capacity per half (mean 1562, +25 sigma)

#define WFRAG_N 19456  // 38 slots * 512 bf16 fragment-packed weights
// wbias layout: [0..63] cz, [64..127] cr, [128..191] ch, [192..207] out_b

typedef unsigned short ushort_t;
typedef unsigned char uchar_t;
typedef short short8 __attribute__((ext_vector_type(8)));   // 8 bf16 (4 VGPRs)
typedef float f32x4 __attribute__((ext_vector_type(4)));

__device__ __forceinline__ float ubf(ushort_t v){ return __uint_as_float(((unsigned)v) << 16); }
__device__ __forceinline__ ushort_t f2b(float f){
  unsigned u = __float_as_uint(f);
  return (ushort_t)((u + 0x7FFFu + ((u >> 16) & 1u)) >> 16);
}
__device__ __forceinline__ float lo16f(unsigned u){ return __uint_as_float(u << 16); }
__device__ __forceinline__ float hi16f(unsigned u){ return __uint_as_float(u & 0xFFFF0000u); }

// ---------------- fused prep: wfrag (direct from raw weights) + biases + bcur zero
__global__ void prepall_kernel(const float* __restrict__ Wz,const float* __restrict__ bz,
                               const float* __restrict__ Wr,const float* __restrict__ br,
                               const float* __restrict__ Wh,const float* __restrict__ bh,
                               const float* __restrict__ Lz,const float* __restrict__ Lzb,
                               const float* __restrict__ Lr,const float* __restrict__ Lrb,
                               const float* __restrict__ Lh,const float* __restrict__ Lhb,
                               const float* __restrict__ oW,const float* __restrict__ ob,
                               short* __restrict__ wfrag, float* __restrict__ wbias,
                               int* __restrict__ bcur){
  int bid = blockIdx.x, tid = threadIdx.x;
  if (bid < 76){
    int idx = bid*256 + tid;   // 0..19455
    int slot = idx >> 9, lane = (idx >> 3) & 63, j = idx & 7;
    int q = lane >> 4, l15 = lane & 15;
    float val;
    if (slot < 36){
      int g, kc, ncol;
      if (slot < 24){ int nt = slot/3; kc = slot - nt*3; ncol = nt*16 + l15;
                      g = (ncol < 64) ? 0 : 1; ncol &= 63; }
      else          { int s2 = slot-24; int nt = s2/3; kc = s2 - nt*3;
                      ncol = nt*16 + l15; g = 2; }
      const float* W = (g==0)?Wz:((g==1)?Wr:Wh);     // [32][64]
      const float* L = (g==0)?Lz:((g==1)?Lr:Lh);     // [128][64]
      int k = kc*32 + q*8 + j;                        // 0..95
      if (k < 32){                                    // fused W@L[:64]
        float s = 0.f;
        for (int m = 0; m < 64; m++) s += W[k*64+m] * L[m*64+ncol];
        val = s;
      } else val = L[(32+k)*64 + ncol];               // L rows 64..127
    } else {
      int kc = slot - 36;
      int k = kc*32 + q*8 + j;                        // 0..63
      val = oW[k*16 + l15];
    }
    wfrag[idx] = (short)f2b(val);
  } else {
    if (tid < 192){
      int g = tid >> 6, j = tid & 63;
      const float* L  = (g==0)?Lz:((g==1)?Lr:Lh);
      const float* bb = (g==0)?bz:((g==1)?br:bh);
      const float* Lb = (g==0)?Lzb:((g==1)?Lrb:Lhb);
      float s = Lb[j];
      for (int m = 0; m < 64; m++) s += bb[m] * L[m*64+j];
      wbias[tid] = s;
    } else if (tid < 208){
      wbias[tid] = ob[tid-192];
    }
    for (int i = tid; i < 1536; i += 256) bcur[i] = 0;
  }
}

// ---------------- scatter: LDS counting-sort by bucket -> coalesced slab writes --
__global__ __launch_bounds__(256) void scatter_kernel(const int* __restrict__ ei,
                                                      int* __restrict__ bcur,
                                                      ushort_t* __restrict__ ssrc16,
                                                      uchar_t* __restrict__ sdst8){
  int t = blockIdx.y;
  __shared__ int cnt[NB];
  __shared__ int lstart[NB];
  __shared__ int gbase[NB];
  __shared__ int wsum[4];
  __shared__ ushort_t spay[CHUNK];
  __shared__ uchar_t  sdlo[CHUNK];
  __shared__ uchar_t  sbk[CHUNK];
  int tid = threadIdx.x;
  cnt[tid] = 0;
  __syncthreads();
  int e0 = blockIdx.x*CHUNK;
  const int* srcs = ei + t*2*EE;
  const int* dsts = ei + t*2*EE + EE;
  int pk[CHUNK/256];
  int ps[CHUNK/256];
  int pd[CHUNK/256];
  #pragma unroll
  for (int i = 0; i < CHUNK/256; i++){
    int e = e0 + i*256 + tid;
    if (e < EE){
      int s = srcs[e], d = dsts[e];
      int b = d / DPB;
      int lr = atomicAdd(&cnt[b], 1);
      pk[i] = (b << 12) | lr;
      ps[i] = s;
      pd[i] = d - b*DPB;
    } else pk[i] = -1;
  }
  __syncthreads();
  {
    int v = cnt[tid];
    int lane = tid & 63, wid = tid >> 6;
    int x = v;
    #pragma unroll
    for (int o = 1; o < 64; o <<= 1){
      int y = __shfl_up(x, o, 64);
      if (lane >= o) x += y;
    }
    if (lane == 63) wsum[wid] = x;
    __syncthreads();
    if (tid == 0){
      int s = 0;
      #pragma unroll
      for (int w = 0; w < 4; w++){ int tmp = wsum[w]; wsum[w] = s; s += tmp; }
    }
    __syncthreads();
    lstart[tid] = x - v + wsum[wid];
    gbase[tid] = (v > 0) ? atomicAdd(&bcur[t*NB + tid], v) : 0;
  }
  __syncthreads();
  #pragma unroll
  for (int i = 0; i < CHUNK/256; i++){
    if (pk[i] >= 0){
      int b = pk[i] >> 12, lr = pk[i] & 4095;
      int pos = lstart[b] + lr;
      spay[pos] = (ushort_t)ps[i];
      sdlo[pos] = (uchar_t)pd[i];
      sbk[pos]  = (uchar_t)b;
    }
  }
  __syncthreads();
  int nE = EE - e0; if (nE > CHUNK) nE = CHUNK;
  for (int i = tid; i < nE; i += 256){
    int b = sbk[i];
    int gpos = gbase[b] + (i - lstart[b]);
    if (gpos < CAP){
      size_t sb = (size_t)(t*NB + b)*CAP + gpos;
      ssrc16[sb] = spay[i];
      sdst8[sb]  = sdlo[i];
    }
  }
}

// ---------------- per-bucket degree -> dinv (reads u8 slab only) ----------------
__global__ __launch_bounds__(256) void degdinv_kernel(const uchar_t* __restrict__ sdst8,
                                                      const int* __restrict__ bcur,
                                                      float* __restrict__ dinv){
  int b = blockIdx.x, t = blockIdx.y, tid = threadIdx.x;
  __shared__ int cnt[DPB];
  for (int i = tid; i < DPB; i += 256) cnt[i] = 0;
  __syncthreads();
  int ecnt = bcur[t*NB + b]; if (ecnt > CAP) ecnt = CAP;
  const uchar_t* dp = sdst8 + (size_t)(t*NB + b)*CAP;
  for (int i = tid; i < ecnt; i += 256)
    atomicAdd(&cnt[dp[i]], 1);
  __syncthreads();
  for (int i = tid; i < DPB; i += 256){
    int n = b*DPB + i;
    if (n < NN) dinv[t*NN + n] = rsqrtf((float)(cnt[i] + 1));  // +1 self loop
  }
}

// ---------------- convert + pre-scale: xbs[t][n][f] = bf16(dinv[t][n] * x[t][n][f])
__global__ void cvtscale_kernel(const float4* __restrict__ x4,
                                const float* __restrict__ dinv,
                                ushort4* __restrict__ xb4){
  int i = blockIdx.x*256 + threadIdx.x;     // float4 index, 2,400,000 total
  if (i < TT*NN*8){
    float dn = dinv[i >> 3];
    float4 v = x4[i];
    ushort4 o;
    o.x = f2b(v.x*dn); o.y = f2b(v.y*dn); o.z = f2b(v.z*dn); o.w = f2b(v.w*dn);
    xb4[i] = o;
  }
}

// ---------------- bucket gather v4: pre-scaled rows -> pure-sum inner loop ------
// 8 edges/wave-iter (8 lanes x uint2 = 4 bf16 features each); dn from local deg.
// agg[n] = dn*(sum_s xbs[s] + xbs[n]),  dn = rsqrt(deg+1)
// Grid 3072; XCD t-affinity: w=(bid&7)*384+(bid>>3); t=w>>9; b=(w&511)>>1; sb=w&1.
__global__ __launch_bounds__(256) void gatherb_kernel(const ushort_t* __restrict__ xbs,
                                                      const ushort_t* __restrict__ ssrc16,
                                                      const uchar_t* __restrict__ sdst8,
                                                      const int* __restrict__ bcur,
                                                      ushort_t* __restrict__ aggb){
  int l = blockIdx.x;
  int wk = ((l & 7) * 384) + (l >> 3);
  int t = wk >> 9;
  int r9 = wk & 511;
  int b = r9 >> 1;
  int sb = r9 & 1;
  int DLO0 = sb * HDPB;                 // my dst half [DLO0, DLO0+98)
  int tid = threadIdx.x;
  __shared__ ushort_t ssrc[HCAP];       // 5 KB srcs sorted by local dlo
  __shared__ int cnt[HDPB+2];
  __shared__ int off[HDPB+2];
  for (int i = tid; i < HDPB+2; i += 256) cnt[i] = 0;
  __syncthreads();
  int ecnt = bcur[t*NB + b]; if (ecnt > CAP) ecnt = CAP;
  size_t slab = (size_t)(t*NB + b)*CAP;
  const ushort_t* sp = ssrc16 + slab;
  const uchar_t*  dp = sdst8 + slab;
  unsigned pe[CAP/256]; int ne = 0;     // (ldlo<<16)|src for my half, in VGPRs
  for (int e = tid; e < ecnt; e += 256){
    unsigned s = sp[e];
    unsigned ld = (unsigned)dp[e] - (unsigned)DLO0;
    if (ld < (unsigned)HDPB){
      pe[ne++] = (ld << 16) | s;
      atomicAdd(&cnt[ld], 1);
    }
  }
  __syncthreads();
  if (tid == 0){                        // serial exclusive scan over 98 entries
    int s = 0;
    for (int i = 0; i < HDPB; i++){
      int c = cnt[i];
      off[i] = s; cnt[i] = s;           // cnt becomes rank cursor
      s += c;
    }
    off[HDPB] = s;
  }
  __syncthreads();
  for (int k = 0; k < ne; k++){
    unsigned p = pe[k];
    int rr = atomicAdd(&cnt[p >> 16], 1);
    if (rr < HCAP) ssrc[rr] = (ushort_t)(p & 0xFFFFu);
  }
  __syncthreads();
  // reduce: wave wv owns ~25 dsts; 64 lanes = 8 edges x 8 uint2 feature-quads
  int wv = tid >> 6, lane = tid & 63;
  int eg = lane >> 3;                   // edge group 0..7
  int fp = lane & 7;                    // uint2 index (4 bf16)
  const uint2* xb2 = (const uint2*)xbs + (size_t)t*NN*8;
  uint2* agg2 = (uint2*)aggb + (size_t)t*NN*8;
  int d0  = (wv < 2) ? wv*25 : 50 + (wv-2)*24;
  int ndw = (wv < 2) ? 25 : 24;
  for (int dd = 0; dd < ndw; dd++){
    int ld = d0 + dd;
    int e0 = off[ld], e1 = off[ld+1];
    float a0 = 0.f, a1 = 0.f, a2 = 0.f, a3 = 0.f;
    int base = e0;
    int i0 = e0 + eg;
    bool vc = (i0 < e1);
    int s0 = (int)ssrc[vc ? i0 : 0];
    uint2 rvc = xb2[s0*8 + fp];
    float mc = vc ? 1.f : 0.f;
    while (base < e1){
      int nbase = base + 8;
      int inx = nbase + eg;
      bool vn = (inx < e1);
      int sn = (int)ssrc[vn ? inx : 0];
      uint2 rvn = xb2[sn*8 + fp];       // prefetch next (in flight during fma)
      a0 += mc * lo16f(rvc.x);
      a1 += mc * hi16f(rvc.x);
      a2 += mc * lo16f(rvc.y);
      a3 += mc * hi16f(rvc.y);
      mc = vn ? 1.f : 0.f;
      rvc = rvn;
      base = nbase;
    }
    a0 += __shfl_xor(a0, 8, 64); a0 += __shfl_xor(a0, 16, 64); a0 += __shfl_xor(a0, 32, 64);
    a1 += __shfl_xor(a1, 8, 64); a1 += __shfl_xor(a1, 16, 64); a1 += __shfl_xor(a1, 32, 64);
    a2 += __shfl_xor(a2, 8, 64); a2 += __shfl_xor(a2, 16, 64); a2 += __shfl_xor(a2, 32, 64);
    a3 += __shfl_xor(a3, 8, 64); a3 += __shfl_xor(a3, 16, 64); a3 += __shfl_xor(a3, 32, 64);
    int n = b*DPB + DLO0 + ld;
    if (eg == 0 && n < NN){
      float dn = rsqrtf((float)(e1 - e0 + 1));   // local degree -> dinv
      uint2 sv = xb2[n*8 + fp];                  // xbs[n] = dn*x[n] (self term)
      float o0 = dn*(a0 + lo16f(sv.x));
      float o1 = dn*(a1 + hi16f(sv.x));
      float o2 = dn*(a2 + lo16f(sv.y));
      float o3 = dn*(a3 + hi16f(sv.y));
      uint2 pk;
      pk.x = (unsigned)f2b(o0) | ((unsigned)f2b(o1) << 16);
      pk.y = (unsigned)f2b(o2) | ((unsigned)f2b(o3) << 16);
      agg2[(size_t)n*8 + fp] = pk;
    }
  }
}

// ---------------- ALL GRU steps, MFMA version; h LDS-resident; out fused --------
__global__ __launch_bounds__(256) void gates_kernel(const ushort_t* __restrict__ aggb,
                                                    const float* __restrict__ wbias,
                                                    const short* __restrict__ wfrag,
                                                    float* __restrict__ out){
  __shared__ __align__(16) short As[2048];    // 64 x 32  (4 KB)
  __shared__ __align__(16) short Hsp[4096];   // 64 x 64  (8 KB)
  __shared__ __align__(16) short HRp[4096];   // 64 x 64  (8 KB)
  int tid = threadIdx.x;
  int nb = blockIdx.x*64;
  int wv = tid >> 6, lane = tid & 63;
  int q = lane >> 4, l15 = lane & 15;
  #pragma unroll
  for (int r = 0; r < 8; r++) ((int*)Hsp)[tid + 256*r] = 0;
  short8 wz[3], wr[3], wh[3];
  #pragma unroll
  for (int kc = 0; kc < 3; kc++){
    wz[kc] = ((const short8*)wfrag)[(wv*3 + kc)*64 + lane];
    wr[kc] = ((const short8*)wfrag)[((wv+4)*3 + kc)*64 + lane];
    wh[kc] = ((const short8*)wfrag)[(24 + wv*3 + kc)*64 + lane];
  }
  int jz = wv*16 + l15;
  float cz = wbias[jz], cr = wbias[64 + jz], ch = wbias[128 + jz];
  int hidx = ((jz >> 3)*64)*8 + (jz & 7);
  f32x4 accZ[4], accR[4];
  for (int t = 0; t < TT; t++){
    {
      int n = tid >> 2, c = tid & 3, gn = nb + n;
      uint4 v = make_uint4(0,0,0,0);
      if (gn < NN) v = ((const uint4*)aggb)[((size_t)t*NN + gn)*4 + (size_t)c];
      *(uint4*)&As[(c*64 + n)*8] = v;
    }
    __syncthreads();
    #pragma unroll
    for (int mt = 0; mt < 4; mt++){
      short8 fa  = *(const short8*)&As [((q)*64   + mt*16 + l15)*8];
      short8 fh0 = *(const short8*)&Hsp[((q)*64   + mt*16 + l15)*8];
      short8 fh1 = *(const short8*)&Hsp[((4+q)*64 + mt*16 + l15)*8];
      f32x4 az = {0.f,0.f,0.f,0.f}, ar = {0.f,0.f,0.f,0.f};
      az = __builtin_amdgcn_mfma_f32_16x16x32_bf16(fa,  wz[0], az, 0,0,0);
      az = __builtin_amdgcn_mfma_f32_16x16x32_bf16(fh0, wz[1], az, 0,0,0);
      az = __builtin_amdgcn_mfma_f32_16x16x32_bf16(fh1, wz[2], az, 0,0,0);
      ar = __builtin_amdgcn_mfma_f32_16x16x32_bf16(fa,  wr[0], ar, 0,0,0);
      ar = __builtin_amdgcn_mfma_f32_16x16x32_bf16(fh0, wr[1], ar, 0,0,0);
      ar = __builtin_amdgcn_mfma_f32_16x16x32_bf16(fh1, wr[2], ar, 0,0,0);
      accZ[mt] = az; accR[mt] = ar;
    }
    #pragma unroll
    for (int mt = 0; mt < 4; mt++){
      #pragma unroll
      for (int e = 0; e < 4; e++){
        int node = mt*16 + q*4 + e;
        float z = 1.f/(1.f + __expf(-(accZ[mt][e] + cz)));
        float r = 1.f/(1.f + __expf(-(accR[mt][e] + cr)));
        float hold = ubf((ushort_t)Hsp[hidx + node*8]);
        HRp[hidx + node*8] = (short)f2b(hold * r);
        accZ[mt][e] = z;
      }
    }
    __syncthreads();
    #pragma unroll
    for (int mt = 0; mt < 4; mt++){
      short8 fa  = *(const short8*)&As [((q)*64   + mt*16 + l15)*8];
      short8 fr0 = *(const short8*)&HRp[((q)*64   + mt*16 + l15)*8];
      short8 fr1 = *(const short8*)&HRp[((4+q)*64 + mt*16 + l15)*8];
      f32x4 ahh = {0.f,0.f,0.f,0.f};
      ahh = __builtin_amdgcn_mfma_f32_16x16x32_bf16(fa,  wh[0], ahh, 0,0,0);
      ahh = __builtin_amdgcn_mfma_f32_16x16x32_bf16(fr0, wh[1], ahh, 0,0,0);
      ahh = __builtin_amdgcn_mfma_f32_16x16x32_bf16(fr1, wh[2], ahh, 0,0,0);
      accR[mt] = ahh;
    }
    float hn[4][4];
    #pragma unroll
    for (int mt = 0; mt < 4; mt++){
      #pragma unroll
      for (int e = 0; e < 4; e++){
        int node = mt*16 + q*4 + e;
        float xv = accR[mt][e] + ch;
        float ex = __expf(-2.f*fabsf(xv));
        float th = (1.f - ex)/(1.f + ex);
        th = (xv < 0.f) ? -th : th;
        float hold = ubf((ushort_t)Hsp[hidx + node*8]);
        float z = accZ[mt][e];
        hn[mt][e] = z*hold + (1.f - z)*th;
      }
    }
    __syncthreads();
    #pragma unroll
    for (int mt = 0; mt < 4; mt++){
      #pragma unroll
      for (int e = 0; e < 4; e++){
        int node = mt*16 + q*4 + e;
        Hsp[hidx + node*8] = (short)f2b(hn[mt][e]);
      }
    }
  }
  __syncthreads();
  short8 wo0 = ((const short8*)wfrag)[36*64 + lane];
  short8 wo1 = ((const short8*)wfrag)[37*64 + lane];
  short8 f0 = *(const short8*)&Hsp[((q)*64   + wv*16 + l15)*8];
  short8 f1 = *(const short8*)&Hsp[((4+q)*64 + wv*16 + l15)*8];
  f32x4 ao = {0.f,0.f,0.f,0.f};
  ao = __builtin_amdgcn_mfma_f32_16x16x32_bf16(f0, wo0, ao, 0,0,0);
  ao = __builtin_amdgcn_mfma_f32_16x16x32_bf16(f1, wo1, ao, 0,0,0);
  float ob = wbias[192 + l15];
  #pragma unroll
  for (int e = 0; e < 4; e++){
    int gn = nb + wv*16 + q*4 + e;
    if (gn < NN) out[gn*OO + l15] = ao[e] + ob;
  }
}

extern "C" void kernel_launch(void* const* d_in, const int* in_sizes, int n_in,
                              void* d_out, int out_size, void* d_ws, size_t ws_size,
                              hipStream_t stream) {
  const float* xs = (const float*)d_in[0];
  const int*   ei = (const int*)d_in[1];
  float* out = (float*)d_out;
  char* ws = (char*)d_ws;
  // workspace layout (bytes); total ~58.5 MB
  ushort_t*  aggb   = (ushort_t*)(ws + 0);           // 19,200,000
  ushort_t*  xbs    = (ushort_t*)(ws + 19200000);    // 19,200,000 (pre-scaled bf16)
  ushort_t*  ssrc16 = (ushort_t*)(ws + 38400000);    // 12,582,912
  uchar_t*   sdst8  = (uchar_t*) (ws + 50982912);    //  6,291,456
  float*     dinv   = (float*)   (ws + 57274368);    //  1,200,000
  int*       bcur   = (int*)     (ws + 58474368);    //  6,144
  short*     wfrag  = (short*)   (ws + 58480512);    //  38,912
  float*     wbias  = (float*)   (ws + 58519424);    //  832 -> end 58,520,256

  prepall_kernel<<<77, 256, 0, stream>>>(
      (const float*)d_in[2],(const float*)d_in[3],(const float*)d_in[4],(const float*)d_in[5],
      (const float*)d_in[6],(const float*)d_in[7],(const float*)d_in[8],(const float*)d_in[9],
      (const float*)d_in[10],(const float*)d_in[11],(const float*)d_in[12],(const float*)d_in[13],
      (const float*)d_in[14],(const float*)d_in[15], wfrag, wbias, bcur);
  scatter_kernel<<<dim3((EE + CHUNK-1)/CHUNK, TT), 256, 0, stream>>>(ei, bcur, ssrc16, sdst8);
  degdinv_kernel<<<dim3(NB, TT), 256, 0, stream>>>(sdst8, bcur, dinv);
  cvtscale_kernel<<<(TT*NN*8 + 255)/256, 256, 0, stream>>>((const float4*)xs, dinv, (ushort4*)xbs);
  gatherb_kernel<<<NB*TT*2, 256, 0, stream>>>(xbs, ssrc16, sdst8, bcur, aggb);
  gates_kernel<<<(NN + 63)/64, 256, 0, stream>>>(aggb, wbias, wfrag, out);
}